// Round 8
// baseline (397.720 us; speedup 1.0000x reference)
//
#include <hip/hip_runtime.h>

#define NN 50000
#define NE 400000
#define GSTAT 2048

typedef short bf16x8 __attribute__((ext_vector_type(8)));
typedef float f32x4 __attribute__((ext_vector_type(4)));

__device__ __forceinline__ float lrelu01(float v) { return v >= 0.f ? v : 0.01f * v; }
__device__ __forceinline__ float lrelu02(float v) { return v >= 0.f ? v : 0.2f * v; }

__device__ __forceinline__ ushort f2bf(float f) {
  union { float f; unsigned u; } v; v.f = f;
  unsigned u = v.u;
  return (ushort)((u + 0x7FFFu + ((u >> 16) & 1u)) >> 16);
}
__device__ __forceinline__ float bf2f(ushort u) {
  union { unsigned u; float f; } v; v.u = ((unsigned)u) << 16;
  return v.f;
}

// ---------------- weight prep: all 5 transposes fused ----------------
__global__ void wprep(const float* __restrict__ w1, const float* __restrict__ gw,
                      const float* __restrict__ w3, const float* __restrict__ w4,
                      const float* __restrict__ w5,
                      ushort* __restrict__ w1T, ushort* __restrict__ gwT,
                      ushort* __restrict__ w3T, ushort* __restrict__ w4T,
                      ushort* __restrict__ w5T) {
  int i = blockIdx.x * 256 + threadIdx.x;
  const float* W; ushort* WT; int K, N, j;
  if (i < 65536)        { W = w1; WT = w1T; K = 256; N = 256; j = i; }
  else if (i < 196608)  { W = gw; WT = gwT; K = 256; N = 512; j = i - 65536; }
  else if (i < 204800)  { W = w3; WT = w3T; K = 128; N = 64;  j = i - 196608; }
  else if (i < 206848)  { W = w4; WT = w4T; K = 64;  N = 32;  j = i - 204800; }
  else if (i < 207360)  { W = w5; WT = w5T; K = 32;  N = 16;  j = i - 206848; }
  else return;
  int k = j / N, c = j % N;
  WT[(size_t)c * K + k] = f2bf(W[(size_t)j]);
}

// ---------------- CSR build ----------------
__global__ void count_kernel(const int* __restrict__ dst, int* __restrict__ counts, int e) {
  int i = blockIdx.x * 256 + threadIdx.x;
  if (i < e) atomicAdd(&counts[dst[i]], 1);
}

__global__ __launch_bounds__(256) void block_count_sum(const int* __restrict__ counts,
                                                       int* __restrict__ bsum,
                                                       float* __restrict__ dinv, int n) {
  int i = blockIdx.x * 256 + threadIdx.x;
  int c = (i < n) ? counts[i] : 0;
  if (i < n) dinv[i] = rsqrtf((float)c + 1.0f);
  int s = c;
#pragma unroll
  for (int off = 32; off > 0; off >>= 1) s += __shfl_down(s, off);
  __shared__ int ws[4];
  if ((threadIdx.x & 63) == 0) ws[threadIdx.x >> 6] = s;
  __syncthreads();
  if (threadIdx.x == 0) bsum[blockIdx.x] = ws[0] + ws[1] + ws[2] + ws[3];
}

__global__ __launch_bounds__(256) void scan_bsum(int* __restrict__ bsum, int nb) {
  __shared__ int sh[256];
  int v = (threadIdx.x < nb) ? bsum[threadIdx.x] : 0;
  sh[threadIdx.x] = v;
  __syncthreads();
  for (int off = 1; off < 256; off <<= 1) {
    int t = (threadIdx.x >= off) ? sh[threadIdx.x - off] : 0;
    __syncthreads();
    sh[threadIdx.x] += t;
    __syncthreads();
  }
  if (threadIdx.x < nb) bsum[threadIdx.x] = sh[threadIdx.x] - v;
}

__global__ __launch_bounds__(256) void row_start_kernel(const int* __restrict__ counts,
                                                        const int* __restrict__ bsum,
                                                        int* __restrict__ row_start, int n) {
  __shared__ int sh[256];
  int i = blockIdx.x * 256 + threadIdx.x;
  int c = (i < n) ? counts[i] : 0;
  sh[threadIdx.x] = c;
  __syncthreads();
  for (int off = 1; off < 256; off <<= 1) {
    int t = (threadIdx.x >= off) ? sh[threadIdx.x - off] : 0;
    __syncthreads();
    sh[threadIdx.x] += t;
    __syncthreads();
  }
  int incl = sh[threadIdx.x];
  int base = bsum[blockIdx.x];
  if (i < n) row_start[i] = base + incl - c;
  if (i == n - 1) row_start[n] = base + incl;
}

__global__ void fill_kernel(const int* __restrict__ src, const int* __restrict__ dst,
                            const int* __restrict__ row_start, int* __restrict__ cursor,
                            int* __restrict__ csr, int e) {
  int i = blockIdx.x * 256 + threadIdx.x;
  if (i >= e) return;
  int d = dst[i];
  int pos = atomicAdd(&cursor[d], 1);
  csr[row_start[d] + pos] = src[i];
}

// ---------------- GEMM 1: A fp32 (x), bf16 out, rowscale ----------------
__global__ __launch_bounds__(256) void gemm_mfma_x(const float* __restrict__ A,
                                                   const ushort* __restrict__ BT,
                                                   ushort* __restrict__ C,
                                                   int M, int K, int N,
                                                   const float* __restrict__ rowscale) {
  __shared__ ushort As[128][40];
  __shared__ ushort Bs[128][40];
  const int tid = threadIdx.x;
  const int bm = blockIdx.x * 128;
  const int bn = blockIdx.y * 128;
  const int wave = tid >> 6, lane = tid & 63;
  const int wr = (wave >> 1) * 64;
  const int wc = (wave & 1) * 64;
  const int lr = lane & 15;
  const int lk = (lane >> 4) * 8;

  f32x4 acc[4][4];
#pragma unroll
  for (int m = 0; m < 4; ++m)
#pragma unroll
    for (int n = 0; n < 4; ++n)
#pragma unroll
      for (int q = 0; q < 4; ++q) acc[m][n][q] = 0.f;

  for (int k0 = 0; k0 < K; k0 += 32) {
#pragma unroll
    for (int it = 0; it < 2; ++it) {
      int s = tid + it * 256;
      int r = s >> 2;
      int c = (s & 3) * 8;
      int grow = bm + r; if (grow >= M) grow = M - 1;
      float4 va = *reinterpret_cast<const float4*>(&A[(size_t)grow * K + k0 + c]);
      float4 vb = *reinterpret_cast<const float4*>(&A[(size_t)grow * K + k0 + c + 4]);
      ushort4 lo = make_ushort4(f2bf(va.x), f2bf(va.y), f2bf(va.z), f2bf(va.w));
      ushort4 hi = make_ushort4(f2bf(vb.x), f2bf(vb.y), f2bf(vb.z), f2bf(vb.w));
      *reinterpret_cast<ushort4*>(&As[r][c]) = lo;
      *reinterpret_cast<ushort4*>(&As[r][c + 4]) = hi;
    }
#pragma unroll
    for (int it = 0; it < 2; ++it) {
      int s = tid + it * 256;
      int r = s >> 2;
      int c = (s & 3) * 8;
      int4 v = *reinterpret_cast<const int4*>(&BT[(size_t)(bn + r) * K + k0 + c]);
      *reinterpret_cast<int4*>(&Bs[r][c]) = v;
    }
    __syncthreads();

    bf16x8 af[4], bfr[4];
#pragma unroll
    for (int m = 0; m < 4; ++m)
      af[m] = *reinterpret_cast<const bf16x8*>(&As[wr + m * 16 + lr][lk]);
#pragma unroll
    for (int n = 0; n < 4; ++n)
      bfr[n] = *reinterpret_cast<const bf16x8*>(&Bs[wc + n * 16 + lr][lk]);
#pragma unroll
    for (int m = 0; m < 4; ++m)
#pragma unroll
      for (int n = 0; n < 4; ++n)
        acc[m][n] = __builtin_amdgcn_mfma_f32_16x16x32_bf16(af[m], bfr[n], acc[m][n], 0, 0, 0);
    __syncthreads();
  }

  const int rbase = (lane >> 4) * 4;
  const int cbase = lane & 15;
#pragma unroll
  for (int m = 0; m < 4; ++m) {
#pragma unroll
    for (int q = 0; q < 4; ++q) {
      int row = bm + wr + m * 16 + rbase + q;
      if (row >= M) continue;
      float sc = rowscale ? rowscale[row] : 1.f;
#pragma unroll
      for (int n = 0; n < 4; ++n) {
        int col = bn + wc + n * 16 + cbase;
        C[(size_t)row * N + col] = f2bf(acc[m][n][q] * sc);
      }
    }
  }
}

// ---------------- GEMM with fused BN+lrelu on A (raw bf16 + stats) ----------------
__global__ __launch_bounds__(256) void gemm_mfma_bn(const ushort* __restrict__ A,
                                                    const ushort* __restrict__ BT,
                                                    ushort* __restrict__ C,
                                                    int M, int K, int N,
                                                    const float* __restrict__ rowscale,
                                                    const float* __restrict__ stats,
                                                    const float* __restrict__ gamma,
                                                    const float* __restrict__ beta) {
  __shared__ ushort As[128][40];
  __shared__ ushort Bs[128][40];
  __shared__ float scl[256], shl[256];
  const int tid = threadIdx.x;
  const float inv_n = 1.0f / (float)NN;
  for (int k = tid; k < K; k += 256) {
    float mean = stats[k] * inv_n;
    float var = stats[K + k] * inv_n - mean * mean;
    float sc = gamma[k] * rsqrtf(var + 1e-5f);
    scl[k] = sc;
    shl[k] = beta[k] - mean * sc;
  }
  const int bm = blockIdx.x * 128;
  const int bn = blockIdx.y * 128;
  const int wave = tid >> 6, lane = tid & 63;
  const int wr = (wave >> 1) * 64;
  const int wc = (wave & 1) * 64;
  const int lr = lane & 15;
  const int lk = (lane >> 4) * 8;

  f32x4 acc[4][4];
#pragma unroll
  for (int m = 0; m < 4; ++m)
#pragma unroll
    for (int n = 0; n < 4; ++n)
#pragma unroll
      for (int q = 0; q < 4; ++q) acc[m][n][q] = 0.f;
  __syncthreads();

  for (int k0 = 0; k0 < K; k0 += 32) {
#pragma unroll
    for (int it = 0; it < 2; ++it) {
      int s = tid + it * 256;
      int r = s >> 2;
      int c = (s & 3) * 8;
      int grow = bm + r; if (grow >= M) grow = M - 1;
      int4 v = *reinterpret_cast<const int4*>(&A[(size_t)grow * K + k0 + c]);
      ushort* u = reinterpret_cast<ushort*>(&v);
      ushort tmp[8];
#pragma unroll
      for (int j = 0; j < 8; ++j) {
        float f = bf2f(u[j]) * scl[k0 + c + j] + shl[k0 + c + j];
        tmp[j] = f2bf(f >= 0.f ? f : 0.01f * f);
      }
      *reinterpret_cast<int4*>(&As[r][c]) = *reinterpret_cast<int4*>(tmp);
    }
#pragma unroll
    for (int it = 0; it < 2; ++it) {
      int s = tid + it * 256;
      int r = s >> 2;
      int c = (s & 3) * 8;
      int4 v = *reinterpret_cast<const int4*>(&BT[(size_t)(bn + r) * K + k0 + c]);
      *reinterpret_cast<int4*>(&Bs[r][c]) = v;
    }
    __syncthreads();

    bf16x8 af[4], bfr[4];
#pragma unroll
    for (int m = 0; m < 4; ++m)
      af[m] = *reinterpret_cast<const bf16x8*>(&As[wr + m * 16 + lr][lk]);
#pragma unroll
    for (int n = 0; n < 4; ++n)
      bfr[n] = *reinterpret_cast<const bf16x8*>(&Bs[wc + n * 16 + lr][lk]);
#pragma unroll
    for (int m = 0; m < 4; ++m)
#pragma unroll
      for (int n = 0; n < 4; ++n)
        acc[m][n] = __builtin_amdgcn_mfma_f32_16x16x32_bf16(af[m], bfr[n], acc[m][n], 0, 0, 0);
    __syncthreads();
  }

  const int rbase = (lane >> 4) * 4;
  const int cbase = lane & 15;
#pragma unroll
  for (int m = 0; m < 4; ++m) {
#pragma unroll
    for (int q = 0; q < 4; ++q) {
      int row = bm + wr + m * 16 + rbase + q;
      if (row >= M) continue;
      float sc = rowscale ? rowscale[row] : 1.f;
#pragma unroll
      for (int n = 0; n < 4; ++n) {
        int col = bn + wc + n * 16 + cbase;
        C[(size_t)row * N + col] = f2bf(acc[m][n][q] * sc);
      }
    }
  }
}

// ---------------- small-N GEMM with fused BN+lrelu on A ----------------
template <int TN>
__global__ __launch_bounds__(256) void gemm_mfma_n_bn(const ushort* __restrict__ A,
                                                      const ushort* __restrict__ BT,
                                                      ushort* __restrict__ C,
                                                      int M, int K,
                                                      const float* __restrict__ rowscale,
                                                      const float* __restrict__ stats,
                                                      const float* __restrict__ gamma,
                                                      const float* __restrict__ beta) {
  __shared__ ushort As[128][40];
  __shared__ ushort Bs[TN][40];
  __shared__ float scl[128], shl[128];
  const int tid = threadIdx.x;
  const float inv_n = 1.0f / (float)NN;
  if (tid < K) {
    float mean = stats[tid] * inv_n;
    float var = stats[K + tid] * inv_n - mean * mean;
    float sc = gamma[tid] * rsqrtf(var + 1e-5f);
    scl[tid] = sc;
    shl[tid] = beta[tid] - mean * sc;
  }
  const int bm = blockIdx.x * 128;
  const int wave = tid >> 6, lane = tid & 63;
  const int wr = wave * 32;
  const int lr = lane & 15;
  const int lk = (lane >> 4) * 8;
  constexpr int NF = TN / 16;

  f32x4 acc[2][NF];
#pragma unroll
  for (int m = 0; m < 2; ++m)
#pragma unroll
    for (int n = 0; n < NF; ++n)
#pragma unroll
      for (int q = 0; q < 4; ++q) acc[m][n][q] = 0.f;
  __syncthreads();

  for (int k0 = 0; k0 < K; k0 += 32) {
#pragma unroll
    for (int it = 0; it < 2; ++it) {
      int s = tid + it * 256;
      int r = s >> 2;
      int c = (s & 3) * 8;
      int grow = bm + r; if (grow >= M) grow = M - 1;
      int4 v = *reinterpret_cast<const int4*>(&A[(size_t)grow * K + k0 + c]);
      ushort* u = reinterpret_cast<ushort*>(&v);
      ushort tmp[8];
#pragma unroll
      for (int j = 0; j < 8; ++j) {
        float f = bf2f(u[j]) * scl[k0 + c + j] + shl[k0 + c + j];
        tmp[j] = f2bf(f >= 0.f ? f : 0.01f * f);
      }
      *reinterpret_cast<int4*>(&As[r][c]) = *reinterpret_cast<int4*>(tmp);
    }
    if (tid < TN * 4) {
      int r = tid >> 2;
      int c = (tid & 3) * 8;
      int4 v = *reinterpret_cast<const int4*>(&BT[(size_t)r * K + k0 + c]);
      *reinterpret_cast<int4*>(&Bs[r][c]) = v;
    }
    __syncthreads();

    bf16x8 af[2], bfr[NF];
#pragma unroll
    for (int m = 0; m < 2; ++m)
      af[m] = *reinterpret_cast<const bf16x8*>(&As[wr + m * 16 + lr][lk]);
#pragma unroll
    for (int n = 0; n < NF; ++n)
      bfr[n] = *reinterpret_cast<const bf16x8*>(&Bs[n * 16 + lr][lk]);
#pragma unroll
    for (int m = 0; m < 2; ++m)
#pragma unroll
      for (int n = 0; n < NF; ++n)
        acc[m][n] = __builtin_amdgcn_mfma_f32_16x16x32_bf16(af[m], bfr[n], acc[m][n], 0, 0, 0);
    __syncthreads();
  }

  const int rbase = (lane >> 4) * 4;
  const int cbase = lane & 15;
#pragma unroll
  for (int m = 0; m < 2; ++m) {
#pragma unroll
    for (int q = 0; q < 4; ++q) {
      int row = bm + wr + m * 16 + rbase + q;
      if (row >= M) continue;
      float sc = rowscale ? rowscale[row] : 1.f;
#pragma unroll
      for (int n = 0; n < NF; ++n) {
        int col = n * 16 + cbase;
        C[(size_t)row * TN + col] = f2bf(acc[m][n][q] * sc);
      }
    }
  }
}

// ---------------- GCN agg + fused BN stats (int4 gathers, x4 unroll) ----------------
template <int F>
__global__ __launch_bounds__(256) void gcn_agg_stats(const ushort* __restrict__ h,
                                                     const int* __restrict__ row_start,
                                                     const int* __restrict__ csr,
                                                     const float* __restrict__ dinv,
                                                     ushort* __restrict__ out,
                                                     float* __restrict__ partials, int n) {
  constexpr int LPN = F / 8;
  constexpr int NPB = 256 / LPN;
  const int tid = threadIdx.x;
  const int sub = tid / LPN;
  const int f8 = (tid % LPN) * 8;
  float ps[8], pq[8];
#pragma unroll
  for (int j = 0; j < 8; ++j) { ps[j] = 0.f; pq[j] = 0.f; }

  for (int node = blockIdx.x * NPB + sub; node < n; node += GSTAT * NPB) {
    float di = dinv[node];
    float a[8];
    {
      int4 v = *reinterpret_cast<const int4*>(&h[(size_t)node * F + f8]);
      const ushort* u = reinterpret_cast<const ushort*>(&v);
#pragma unroll
      for (int j = 0; j < 8; ++j) a[j] = bf2f(u[j]);
    }
    int s0 = row_start[node], s1 = row_start[node + 1];
    int e = s0;
    for (; e + 3 < s1; e += 4) {
      int sA = csr[e], sB = csr[e + 1], sC = csr[e + 2], sD = csr[e + 3];
      int4 vA = *reinterpret_cast<const int4*>(&h[(size_t)sA * F + f8]);
      int4 vB = *reinterpret_cast<const int4*>(&h[(size_t)sB * F + f8]);
      int4 vC = *reinterpret_cast<const int4*>(&h[(size_t)sC * F + f8]);
      int4 vD = *reinterpret_cast<const int4*>(&h[(size_t)sD * F + f8]);
      const ushort* uA = reinterpret_cast<const ushort*>(&vA);
      const ushort* uB = reinterpret_cast<const ushort*>(&vB);
      const ushort* uC = reinterpret_cast<const ushort*>(&vC);
      const ushort* uD = reinterpret_cast<const ushort*>(&vD);
#pragma unroll
      for (int j = 0; j < 8; ++j)
        a[j] += (bf2f(uA[j]) + bf2f(uB[j])) + (bf2f(uC[j]) + bf2f(uD[j]));
    }
    for (; e < s1; ++e) {
      int sA = csr[e];
      int4 vA = *reinterpret_cast<const int4*>(&h[(size_t)sA * F + f8]);
      const ushort* uA = reinterpret_cast<const ushort*>(&vA);
#pragma unroll
      for (int j = 0; j < 8; ++j) a[j] += bf2f(uA[j]);
    }
    ushort u[8];
#pragma unroll
    for (int j = 0; j < 8; ++j) {
      a[j] *= di;
      u[j] = f2bf(a[j]);
      ps[j] += a[j];
      pq[j] += a[j] * a[j];
    }
    *reinterpret_cast<int4*>(&out[(size_t)node * F + f8]) = *reinterpret_cast<int4*>(u);
  }

  __shared__ float red[NPB][2 * F];
#pragma unroll
  for (int j = 0; j < 8; ++j) {
    red[sub][f8 + j] = ps[j];
    red[sub][F + f8 + j] = pq[j];
  }
  __syncthreads();
  for (int c = tid; c < 2 * F; c += 256) {
    float t = 0.f;
#pragma unroll 4
    for (int s = 0; s < NPB; ++s) t += red[s][c];
    partials[(size_t)c * GSTAT + blockIdx.x] = t;
  }
}

// ---------------- GAT softmax: writes NORMALIZED weights (incl. 0.25/den) ----------------
__global__ __launch_bounds__(256) void gat_softmax_norm(const int* __restrict__ row_start,
                                                        const int* __restrict__ csr,
                                                        const float* __restrict__ asc,
                                                        const float* __restrict__ adc,
                                                        float* __restrict__ alpha,
                                                        float* __restrict__ wnorm, int n) {
  int i = blockIdx.x * 256 + threadIdx.x;
  if (i >= 4 * n) return;
  int node = i >> 2, h = i & 3;
  int s0 = row_start[node], s1 = row_start[node + 1];
  float ad = adc[i];
  float eself = lrelu02(asc[i] + ad);
  float m = eself;
  for (int e = s0; e < s1; ++e) {
    float v = lrelu02(asc[csr[e] * 4 + h] + ad);
    alpha[(size_t)e * 4 + h] = v;
    m = fmaxf(m, v);
  }
  float ws = __expf(eself - m);
  float den = ws;
  for (int e = s0; e < s1; ++e) {
    float w = __expf(alpha[(size_t)e * 4 + h] - m);
    alpha[(size_t)e * 4 + h] = w;
    den += w;
  }
  float coef = 0.25f / (den + 1e-16f);
  wnorm[i] = ws * coef;
  for (int e = s0; e < s1; ++e) alpha[(size_t)e * 4 + h] *= coef;
}

// ---------------- GAT agg v2: head-lane int4 gather + BN stats ----------------
// lane = h*16 + l; per edge: one int4 (8 features of head h) + one broadcast float
__global__ __launch_bounds__(256) void gat_agg_v2(const ushort* __restrict__ hg,
                                                  const int* __restrict__ row_start,
                                                  const int* __restrict__ csr,
                                                  const float* __restrict__ alpha,
                                                  const float* __restrict__ wnorm,
                                                  ushort* __restrict__ out,
                                                  float* __restrict__ partials, int n) {
  const int tid = threadIdx.x;
  const int wave = tid >> 6, lane = tid & 63;
  const int h = lane >> 4;
  const int l = lane & 15;
  const int f8 = l * 8;
  float ps[8], pq[8];
#pragma unroll
  for (int j = 0; j < 8; ++j) { ps[j] = 0.f; pq[j] = 0.f; }

  const ushort* base = hg + h * 128 + f8;
  for (int node = blockIdx.x * 4 + wave; node < n; node += GSTAT * 4) {
    float a[8];
    {
      float w = wnorm[node * 4 + h];
      int4 v = *reinterpret_cast<const int4*>(base + (size_t)node * 512);
      const ushort* u = reinterpret_cast<const ushort*>(&v);
#pragma unroll
      for (int j = 0; j < 8; ++j) a[j] = w * bf2f(u[j]);
    }
    int s0 = row_start[node], s1 = row_start[node + 1];
    int e = s0;
    for (; e + 1 < s1; e += 2) {
      int sA = csr[e], sB = csr[e + 1];
      float wA = alpha[(size_t)e * 4 + h];
      float wB = alpha[(size_t)(e + 1) * 4 + h];
      int4 vA = *reinterpret_cast<const int4*>(base + (size_t)sA * 512);
      int4 vB = *reinterpret_cast<const int4*>(base + (size_t)sB * 512);
      const ushort* uA = reinterpret_cast<const ushort*>(&vA);
      const ushort* uB = reinterpret_cast<const ushort*>(&vB);
#pragma unroll
      for (int j = 0; j < 8; ++j) a[j] += wA * bf2f(uA[j]) + wB * bf2f(uB[j]);
    }
    if (e < s1) {
      int sA = csr[e];
      float wA = alpha[(size_t)e * 4 + h];
      int4 vA = *reinterpret_cast<const int4*>(base + (size_t)sA * 512);
      const ushort* uA = reinterpret_cast<const ushort*>(&vA);
#pragma unroll
      for (int j = 0; j < 8; ++j) a[j] += wA * bf2f(uA[j]);
    }
    // cross-head sum (weights already include 0.25/den)
#pragma unroll
    for (int j = 0; j < 8; ++j) {
      a[j] += __shfl_xor(a[j], 16);
      a[j] += __shfl_xor(a[j], 32);
    }
    if (h == 0) {
      ushort u[8];
#pragma unroll
      for (int j = 0; j < 8; ++j) {
        u[j] = f2bf(a[j]);
        ps[j] += a[j];
        pq[j] += a[j] * a[j];
      }
      *reinterpret_cast<int4*>(&out[(size_t)node * 128 + f8]) = *reinterpret_cast<int4*>(u);
    }
  }

  __shared__ float red[4][256];
  if (h == 0) {
#pragma unroll
    for (int j = 0; j < 8; ++j) {
      red[wave][f8 + j] = ps[j];
      red[wave][128 + f8 + j] = pq[j];
    }
  }
  __syncthreads();
  {
    int c = tid;
    float t = red[0][c] + red[1][c] + red[2][c] + red[3][c];
    partials[(size_t)c * GSTAT + blockIdx.x] = t;
  }
}

// ---------------- stats reduce: one block per column ----------------
__global__ __launch_bounds__(256) void bn_reduce_col(const float* __restrict__ partials,
                                                     float* __restrict__ stats) {
  int c = blockIdx.x;
  float s = 0.f;
  for (int b = threadIdx.x; b < GSTAT; b += 256) s += partials[(size_t)c * GSTAT + b];
#pragma unroll
  for (int off = 32; off > 0; off >>= 1) s += __shfl_down(s, off);
  __shared__ float ws[4];
  if ((threadIdx.x & 63) == 0) ws[threadIdx.x >> 6] = s;
  __syncthreads();
  if (threadIdx.x == 0) stats[c] = ws[0] + ws[1] + ws[2] + ws[3];
}

// ---------------- GAT scores ----------------
__global__ __launch_bounds__(256) void gat_scores_bf(const ushort* __restrict__ hg,
                                                     const float* __restrict__ a_src,
                                                     const float* __restrict__ a_dst,
                                                     float* __restrict__ asc,
                                                     float* __restrict__ adc, int n) {
  int node = blockIdx.x;
  int head = threadIdx.x >> 6;
  int lane = threadIdx.x & 63;
  ushort2 v = *reinterpret_cast<const ushort2*>(&hg[(size_t)node * 512 + head * 128 + lane * 2]);
  float v0 = bf2f(v.x), v1 = bf2f(v.y);
  float s = v0 * a_src[head * 128 + lane * 2] + v1 * a_src[head * 128 + lane * 2 + 1];
  float d = v0 * a_dst[head * 128 + lane * 2] + v1 * a_dst[head * 128 + lane * 2 + 1];
#pragma unroll
  for (int off = 32; off > 0; off >>= 1) {
    s += __shfl_down(s, off);
    d += __shfl_down(d, off);
  }
  if (lane == 0) {
    asc[node * 4 + head] = s;
    adc[node * 4 + head] = d;
  }
}

// ---------------- FC head: fused BN+lrelu + MLP + log_softmax ----------------
__global__ __launch_bounds__(256) void head_kernel_bn(const ushort* __restrict__ h,
                                                      const float* __restrict__ stats,
                                                      const float* __restrict__ g5,
                                                      const float* __restrict__ be5,
                                                      const float* __restrict__ fw1,
                                                      const float* __restrict__ fb1,
                                                      const float* __restrict__ fw2,
                                                      const float* __restrict__ fb2,
                                                      float* __restrict__ out, int n) {
  __shared__ float scl[16], shl[16];
  if (threadIdx.x < 16) {
    const float inv_n = 1.0f / (float)NN;
    int k = threadIdx.x;
    float mean = stats[k] * inv_n;
    float var = stats[16 + k] * inv_n - mean * mean;
    float sc = g5[k] * rsqrtf(var + 1e-5f);
    scl[k] = sc;
    shl[k] = be5[k] - mean * sc;
  }
  __syncthreads();
  int i = blockIdx.x * 256 + threadIdx.x;
  if (i >= n) return;
  int4 ra = *reinterpret_cast<const int4*>(&h[(size_t)i * 16]);
  int4 rb = *reinterpret_cast<const int4*>(&h[(size_t)i * 16 + 8]);
  ushort u[16];
  *reinterpret_cast<int4*>(&u[0]) = ra;
  *reinterpret_cast<int4*>(&u[8]) = rb;
  float xr[16];
#pragma unroll
  for (int k = 0; k < 16; ++k) {
    float v = bf2f(u[k]) * scl[k] + shl[k];
    xr[k] = v >= 0.f ? v : 0.01f * v;
  }
  float z[8];
#pragma unroll
  for (int j = 0; j < 8; ++j) z[j] = fb1[j];
#pragma unroll
  for (int k = 0; k < 16; ++k) {
    float a = xr[k];
#pragma unroll
    for (int j = 0; j < 8; ++j) z[j] += a * fw1[k * 8 + j];
  }
#pragma unroll
  for (int j = 0; j < 8; ++j) z[j] = lrelu01(z[j]);
  float l[3];
#pragma unroll
  for (int j = 0; j < 3; ++j) l[j] = fb2[j];
#pragma unroll
  for (int k = 0; k < 8; ++k) {
    float a = z[k];
#pragma unroll
    for (int j = 0; j < 3; ++j) l[j] += a * fw2[k * 3 + j];
  }
  float mx = fmaxf(l[0], fmaxf(l[1], l[2]));
  float se = __expf(l[0] - mx) + __expf(l[1] - mx) + __expf(l[2] - mx);
  float ls = __logf(se);
#pragma unroll
  for (int j = 0; j < 3; ++j) out[(size_t)i * 3 + j] = l[j] - mx - ls;
}

// ---------------- launch ----------------
extern "C" void kernel_launch(void* const* d_in, const int* in_sizes, int n_in,
                              void* d_out, int out_size, void* d_ws, size_t ws_size,
                              hipStream_t stream) {
  const float* x      = (const float*)d_in[0];
  const int*   ei     = (const int*)d_in[1];
  const int*   srcI   = ei;
  const int*   dstI   = ei + NE;
  const float* w1     = (const float*)d_in[2];
  const float* g1     = (const float*)d_in[4];
  const float* be1    = (const float*)d_in[5];
  const float* gat_w  = (const float*)d_in[6];
  const float* gat_as = (const float*)d_in[7];
  const float* gat_ad = (const float*)d_in[8];
  const float* g2     = (const float*)d_in[10];
  const float* be2    = (const float*)d_in[11];
  const float* w3     = (const float*)d_in[12];
  const float* g3     = (const float*)d_in[14];
  const float* be3    = (const float*)d_in[15];
  const float* w4     = (const float*)d_in[16];
  const float* g4     = (const float*)d_in[18];
  const float* be4    = (const float*)d_in[19];
  const float* w5     = (const float*)d_in[20];
  const float* g5     = (const float*)d_in[22];
  const float* be5    = (const float*)d_in[23];
  const float* fw1    = (const float*)d_in[24];
  const float* fb1    = (const float*)d_in[25];
  const float* fw2    = (const float*)d_in[26];
  const float* fb2    = (const float*)d_in[27];
  float* out = (float*)d_out;

  char* wsp = (char*)d_ws;
  size_t off = 0;
  auto alloc = [&](size_t bytes) -> void* {
    void* p = wsp + off;
    off += (bytes + 255) & ~(size_t)255;
    return p;
  };
  ushort* hw_bf  = (ushort*)alloc((size_t)NN * 512 * 2);
  ushort* r1     = (ushort*)alloc((size_t)NN * 256 * 2);
  ushort* r2     = (ushort*)alloc((size_t)NN * 128 * 2);
  ushort* r3     = (ushort*)alloc((size_t)NN * 64 * 2);
  ushort* r4     = (ushort*)alloc((size_t)NN * 32 * 2);
  ushort* r5     = (ushort*)alloc((size_t)NN * 16 * 2);
  ushort* w1T    = (ushort*)alloc((size_t)256 * 256 * 2);
  ushort* gwT    = (ushort*)alloc((size_t)512 * 256 * 2);
  ushort* w3T    = (ushort*)alloc((size_t)64 * 128 * 2);
  ushort* w4T    = (ushort*)alloc((size_t)32 * 64 * 2);
  ushort* w5T    = (ushort*)alloc((size_t)16 * 32 * 2);
  float*  dinv   = (float*)alloc((size_t)NN * 4);
  int*    counts = (int*)alloc((size_t)NN * 4);
  int*    cursor = (int*)alloc((size_t)NN * 4);
  int*    rstart = (int*)alloc((size_t)(NN + 4) * 4);
  int*    bsum   = (int*)alloc((size_t)256 * 4);
  int*    csr    = (int*)alloc((size_t)NE * 4);
  float*  asc    = (float*)alloc((size_t)NN * 4 * 4);
  float*  adc    = (float*)alloc((size_t)NN * 4 * 4);
  float*  wnorm  = (float*)alloc((size_t)NN * 4 * 4);
  float*  alpha  = (float*)alloc((size_t)NE * 4 * 4);
  float*  stats  = (float*)alloc(2048);
  float*  partials = (float*)alloc((size_t)512 * GSTAT * 4);

  const int egrid = (NE + 255) / 256;
  const int ngrid = (NN + 255) / 256;     // 196
  const int mblocks = (NN + 127) / 128;   // 391

  // CSR build
  hipMemsetAsync(counts, 0, (size_t)NN * 4, stream);
  hipMemsetAsync(cursor, 0, (size_t)NN * 4, stream);
  count_kernel<<<egrid, 256, 0, stream>>>(dstI, counts, NE);
  block_count_sum<<<ngrid, 256, 0, stream>>>(counts, bsum, dinv, NN);
  scan_bsum<<<1, 256, 0, stream>>>(bsum, ngrid);
  row_start_kernel<<<ngrid, 256, 0, stream>>>(counts, bsum, rstart, NN);
  fill_kernel<<<egrid, 256, 0, stream>>>(srcI, dstI, rstart, cursor, csr, NE);

  // weight prep
  wprep<<<810, 256, 0, stream>>>(w1, gat_w, w3, w4, w5, w1T, gwT, w3T, w4T, w5T);

  // ---- Layer 1: GCN 256 -> 256 ----
  gemm_mfma_x<<<dim3(mblocks, 2), 256, 0, stream>>>(x, w1T, hw_bf, NN, 256, 256, dinv);
  gcn_agg_stats<256><<<GSTAT, 256, 0, stream>>>(hw_bf, rstart, csr, dinv, r1, partials, NN);
  bn_reduce_col<<<512, 256, 0, stream>>>(partials, stats);

  // ---- Layer 2: GAT 256 -> 128 (BN1+lrelu fused into A-staging) ----
  gemm_mfma_bn<<<dim3(mblocks, 4), 256, 0, stream>>>(r1, gwT, hw_bf, NN, 256, 512, nullptr,
                                                     stats, g1, be1);
  gat_scores_bf<<<NN, 256, 0, stream>>>(hw_bf, gat_as, gat_ad, asc, adc, NN);
  gat_softmax_norm<<<(4 * NN + 255) / 256, 256, 0, stream>>>(rstart, csr, asc, adc, alpha, wnorm, NN);
  gat_agg_v2<<<GSTAT, 256, 0, stream>>>(hw_bf, rstart, csr, alpha, wnorm, r2, partials, NN);
  bn_reduce_col<<<256, 256, 0, stream>>>(partials, stats);

  // ---- Layer 3: GCN 128 -> 64 (BN2 fused) ----
  gemm_mfma_n_bn<64><<<mblocks, 256, 0, stream>>>(r2, w3T, hw_bf, NN, 128, dinv, stats, g2, be2);
  gcn_agg_stats<64><<<GSTAT, 256, 0, stream>>>(hw_bf, rstart, csr, dinv, r3, partials, NN);
  bn_reduce_col<<<128, 256, 0, stream>>>(partials, stats);

  // ---- Layer 4: GCN 64 -> 32 (BN3 fused) ----
  gemm_mfma_n_bn<32><<<mblocks, 256, 0, stream>>>(r3, w4T, hw_bf, NN, 64, dinv, stats, g3, be3);
  gcn_agg_stats<32><<<GSTAT, 256, 0, stream>>>(hw_bf, rstart, csr, dinv, r4, partials, NN);
  bn_reduce_col<<<64, 256, 0, stream>>>(partials, stats);

  // ---- Layer 5: GCN 32 -> 16 (BN4 fused) ----
  gemm_mfma_n_bn<16><<<mblocks, 256, 0, stream>>>(r4, w5T, hw_bf, NN, 32, dinv, stats, g4, be4);
  gcn_agg_stats<16><<<GSTAT, 256, 0, stream>>>(hw_bf, rstart, csr, dinv, r5, partials, NN);
  bn_reduce_col<<<32, 256, 0, stream>>>(partials, stats);

  // ---- FC head (BN5 fused) + log_softmax ----
  head_kernel_bn<<<ngrid, 256, 0, stream>>>(r5, stats, g5, be5, fw1, fb1, fw2, fb2, out, NN);
}

// Round 9
// 387.331 us; speedup vs baseline: 1.0268x; 1.0268x over previous
//
#include <hip/hip_runtime.h>

#define NN 50000
#define NE 400000
#define GSTAT 2048

typedef short bf16x8 __attribute__((ext_vector_type(8)));
typedef float f32x4 __attribute__((ext_vector_type(4)));

__device__ __forceinline__ float lrelu01(float v) { return v >= 0.f ? v : 0.01f * v; }
__device__ __forceinline__ float lrelu02(float v) { return v >= 0.f ? v : 0.2f * v; }

__device__ __forceinline__ ushort f2bf(float f) {
  union { float f; unsigned u; } v; v.f = f;
  unsigned u = v.u;
  return (ushort)((u + 0x7FFFu + ((u >> 16) & 1u)) >> 16);
}
__device__ __forceinline__ float bf2f(ushort u) {
  union { unsigned u; float f; } v; v.u = ((unsigned)u) << 16;
  return v.f;
}

// ---------------- weight prep: all 5 transposes fused ----------------
__global__ void wprep(const float* __restrict__ w1, const float* __restrict__ gw,
                      const float* __restrict__ w3, const float* __restrict__ w4,
                      const float* __restrict__ w5,
                      ushort* __restrict__ w1T, ushort* __restrict__ gwT,
                      ushort* __restrict__ w3T, ushort* __restrict__ w4T,
                      ushort* __restrict__ w5T) {
  int i = blockIdx.x * 256 + threadIdx.x;
  const float* W; ushort* WT; int K, N, j;
  if (i < 65536)        { W = w1; WT = w1T; K = 256; N = 256; j = i; }
  else if (i < 196608)  { W = gw; WT = gwT; K = 256; N = 512; j = i - 65536; }
  else if (i < 204800)  { W = w3; WT = w3T; K = 128; N = 64;  j = i - 196608; }
  else if (i < 206848)  { W = w4; WT = w4T; K = 64;  N = 32;  j = i - 204800; }
  else if (i < 207360)  { W = w5; WT = w5T; K = 32;  N = 16;  j = i - 206848; }
  else return;
  int k = j / N, c = j % N;
  WT[(size_t)c * K + k] = f2bf(W[(size_t)j]);
}

// ---------------- CSR build ----------------
__global__ void count_kernel(const int* __restrict__ dst, int* __restrict__ counts, int e) {
  int i = blockIdx.x * 256 + threadIdx.x;
  if (i < e) atomicAdd(&counts[dst[i]], 1);
}

__global__ __launch_bounds__(256) void block_count_sum(const int* __restrict__ counts,
                                                       int* __restrict__ bsum,
                                                       float* __restrict__ dinv, int n) {
  int i = blockIdx.x * 256 + threadIdx.x;
  int c = (i < n) ? counts[i] : 0;
  if (i < n) dinv[i] = rsqrtf((float)c + 1.0f);
  int s = c;
#pragma unroll
  for (int off = 32; off > 0; off >>= 1) s += __shfl_down(s, off);
  __shared__ int ws[4];
  if ((threadIdx.x & 63) == 0) ws[threadIdx.x >> 6] = s;
  __syncthreads();
  if (threadIdx.x == 0) bsum[blockIdx.x] = ws[0] + ws[1] + ws[2] + ws[3];
}

__global__ __launch_bounds__(256) void scan_bsum(int* __restrict__ bsum, int nb) {
  __shared__ int sh[256];
  int v = (threadIdx.x < nb) ? bsum[threadIdx.x] : 0;
  sh[threadIdx.x] = v;
  __syncthreads();
  for (int off = 1; off < 256; off <<= 1) {
    int t = (threadIdx.x >= off) ? sh[threadIdx.x - off] : 0;
    __syncthreads();
    sh[threadIdx.x] += t;
    __syncthreads();
  }
  if (threadIdx.x < nb) bsum[threadIdx.x] = sh[threadIdx.x] - v;
}

__global__ __launch_bounds__(256) void row_start_kernel(const int* __restrict__ counts,
                                                        const int* __restrict__ bsum,
                                                        int* __restrict__ row_start, int n) {
  __shared__ int sh[256];
  int i = blockIdx.x * 256 + threadIdx.x;
  int c = (i < n) ? counts[i] : 0;
  sh[threadIdx.x] = c;
  __syncthreads();
  for (int off = 1; off < 256; off <<= 1) {
    int t = (threadIdx.x >= off) ? sh[threadIdx.x - off] : 0;
    __syncthreads();
    sh[threadIdx.x] += t;
    __syncthreads();
  }
  int incl = sh[threadIdx.x];
  int base = bsum[blockIdx.x];
  if (i < n) row_start[i] = base + incl - c;
  if (i == n - 1) row_start[n] = base + incl;
}

__global__ void fill_kernel(const int* __restrict__ src, const int* __restrict__ dst,
                            const int* __restrict__ row_start, int* __restrict__ cursor,
                            int* __restrict__ csr, int e) {
  int i = blockIdx.x * 256 + threadIdx.x;
  if (i >= e) return;
  int d = dst[i];
  int pos = atomicAdd(&cursor[d], 1);
  csr[row_start[d] + pos] = src[i];
}

// ---------------- GEMM 1: A fp32 (x), bf16 out, rowscale ----------------
__global__ __launch_bounds__(256) void gemm_mfma_x(const float* __restrict__ A,
                                                   const ushort* __restrict__ BT,
                                                   ushort* __restrict__ C,
                                                   int M, int K, int N,
                                                   const float* __restrict__ rowscale) {
  __shared__ ushort As[128][40];
  __shared__ ushort Bs[128][40];
  const int tid = threadIdx.x;
  const int bm = blockIdx.x * 128;
  const int bn = blockIdx.y * 128;
  const int wave = tid >> 6, lane = tid & 63;
  const int wr = (wave >> 1) * 64;
  const int wc = (wave & 1) * 64;
  const int lr = lane & 15;
  const int lk = (lane >> 4) * 8;

  f32x4 acc[4][4];
#pragma unroll
  for (int m = 0; m < 4; ++m)
#pragma unroll
    for (int n = 0; n < 4; ++n)
#pragma unroll
      for (int q = 0; q < 4; ++q) acc[m][n][q] = 0.f;

  for (int k0 = 0; k0 < K; k0 += 32) {
#pragma unroll
    for (int it = 0; it < 2; ++it) {
      int s = tid + it * 256;
      int r = s >> 2;
      int c = (s & 3) * 8;
      int grow = bm + r; if (grow >= M) grow = M - 1;
      float4 va = *reinterpret_cast<const float4*>(&A[(size_t)grow * K + k0 + c]);
      float4 vb = *reinterpret_cast<const float4*>(&A[(size_t)grow * K + k0 + c + 4]);
      ushort4 lo = make_ushort4(f2bf(va.x), f2bf(va.y), f2bf(va.z), f2bf(va.w));
      ushort4 hi = make_ushort4(f2bf(vb.x), f2bf(vb.y), f2bf(vb.z), f2bf(vb.w));
      *reinterpret_cast<ushort4*>(&As[r][c]) = lo;
      *reinterpret_cast<ushort4*>(&As[r][c + 4]) = hi;
    }
#pragma unroll
    for (int it = 0; it < 2; ++it) {
      int s = tid + it * 256;
      int r = s >> 2;
      int c = (s & 3) * 8;
      int4 v = *reinterpret_cast<const int4*>(&BT[(size_t)(bn + r) * K + k0 + c]);
      *reinterpret_cast<int4*>(&Bs[r][c]) = v;
    }
    __syncthreads();

    bf16x8 af[4], bfr[4];
#pragma unroll
    for (int m = 0; m < 4; ++m)
      af[m] = *reinterpret_cast<const bf16x8*>(&As[wr + m * 16 + lr][lk]);
#pragma unroll
    for (int n = 0; n < 4; ++n)
      bfr[n] = *reinterpret_cast<const bf16x8*>(&Bs[wc + n * 16 + lr][lk]);
#pragma unroll
    for (int m = 0; m < 4; ++m)
#pragma unroll
      for (int n = 0; n < 4; ++n)
        acc[m][n] = __builtin_amdgcn_mfma_f32_16x16x32_bf16(af[m], bfr[n], acc[m][n], 0, 0, 0);
    __syncthreads();
  }

  const int rbase = (lane >> 4) * 4;
  const int cbase = lane & 15;
#pragma unroll
  for (int m = 0; m < 4; ++m) {
#pragma unroll
    for (int q = 0; q < 4; ++q) {
      int row = bm + wr + m * 16 + rbase + q;
      if (row >= M) continue;
      float sc = rowscale ? rowscale[row] : 1.f;
#pragma unroll
      for (int n = 0; n < 4; ++n) {
        int col = bn + wc + n * 16 + cbase;
        C[(size_t)row * N + col] = f2bf(acc[m][n][q] * sc);
      }
    }
  }
}

// ---------------- GEMM with fused BN+lrelu on A (raw bf16 + stats) ----------------
__global__ __launch_bounds__(256) void gemm_mfma_bn(const ushort* __restrict__ A,
                                                    const ushort* __restrict__ BT,
                                                    ushort* __restrict__ C,
                                                    int M, int K, int N,
                                                    const float* __restrict__ rowscale,
                                                    const float* __restrict__ stats,
                                                    const float* __restrict__ gamma,
                                                    const float* __restrict__ beta) {
  __shared__ ushort As[128][40];
  __shared__ ushort Bs[128][40];
  __shared__ float scl[256], shl[256];
  const int tid = threadIdx.x;
  const float inv_n = 1.0f / (float)NN;
  for (int k = tid; k < K; k += 256) {
    float mean = stats[k] * inv_n;
    float var = stats[K + k] * inv_n - mean * mean;
    float sc = gamma[k] * rsqrtf(var + 1e-5f);
    scl[k] = sc;
    shl[k] = beta[k] - mean * sc;
  }
  const int bm = blockIdx.x * 128;
  const int bn = blockIdx.y * 128;
  const int wave = tid >> 6, lane = tid & 63;
  const int wr = (wave >> 1) * 64;
  const int wc = (wave & 1) * 64;
  const int lr = lane & 15;
  const int lk = (lane >> 4) * 8;

  f32x4 acc[4][4];
#pragma unroll
  for (int m = 0; m < 4; ++m)
#pragma unroll
    for (int n = 0; n < 4; ++n)
#pragma unroll
      for (int q = 0; q < 4; ++q) acc[m][n][q] = 0.f;
  __syncthreads();

  for (int k0 = 0; k0 < K; k0 += 32) {
#pragma unroll
    for (int it = 0; it < 2; ++it) {
      int s = tid + it * 256;
      int r = s >> 2;
      int c = (s & 3) * 8;
      int grow = bm + r; if (grow >= M) grow = M - 1;
      int4 v = *reinterpret_cast<const int4*>(&A[(size_t)grow * K + k0 + c]);
      ushort* u = reinterpret_cast<ushort*>(&v);
      ushort tmp[8];
#pragma unroll
      for (int j = 0; j < 8; ++j) {
        float f = bf2f(u[j]) * scl[k0 + c + j] + shl[k0 + c + j];
        tmp[j] = f2bf(f >= 0.f ? f : 0.01f * f);
      }
      *reinterpret_cast<int4*>(&As[r][c]) = *reinterpret_cast<int4*>(tmp);
    }
#pragma unroll
    for (int it = 0; it < 2; ++it) {
      int s = tid + it * 256;
      int r = s >> 2;
      int c = (s & 3) * 8;
      int4 v = *reinterpret_cast<const int4*>(&BT[(size_t)(bn + r) * K + k0 + c]);
      *reinterpret_cast<int4*>(&Bs[r][c]) = v;
    }
    __syncthreads();

    bf16x8 af[4], bfr[4];
#pragma unroll
    for (int m = 0; m < 4; ++m)
      af[m] = *reinterpret_cast<const bf16x8*>(&As[wr + m * 16 + lr][lk]);
#pragma unroll
    for (int n = 0; n < 4; ++n)
      bfr[n] = *reinterpret_cast<const bf16x8*>(&Bs[wc + n * 16 + lr][lk]);
#pragma unroll
    for (int m = 0; m < 4; ++m)
#pragma unroll
      for (int n = 0; n < 4; ++n)
        acc[m][n] = __builtin_amdgcn_mfma_f32_16x16x32_bf16(af[m], bfr[n], acc[m][n], 0, 0, 0);
    __syncthreads();
  }

  const int rbase = (lane >> 4) * 4;
  const int cbase = lane & 15;
#pragma unroll
  for (int m = 0; m < 4; ++m) {
#pragma unroll
    for (int q = 0; q < 4; ++q) {
      int row = bm + wr + m * 16 + rbase + q;
      if (row >= M) continue;
      float sc = rowscale ? rowscale[row] : 1.f;
#pragma unroll
      for (int n = 0; n < 4; ++n) {
        int col = bn + wc + n * 16 + cbase;
        C[(size_t)row * N + col] = f2bf(acc[m][n][q] * sc);
      }
    }
  }
}

// ---------------- small-N GEMM with fused BN+lrelu on A ----------------
template <int TN>
__global__ __launch_bounds__(256) void gemm_mfma_n_bn(const ushort* __restrict__ A,
                                                      const ushort* __restrict__ BT,
                                                      ushort* __restrict__ C,
                                                      int M, int K,
                                                      const float* __restrict__ rowscale,
                                                      const float* __restrict__ stats,
                                                      const float* __restrict__ gamma,
                                                      const float* __restrict__ beta) {
  __shared__ ushort As[128][40];
  __shared__ ushort Bs[TN][40];
  __shared__ float scl[128], shl[128];
  const int tid = threadIdx.x;
  const float inv_n = 1.0f / (float)NN;
  if (tid < K) {
    float mean = stats[tid] * inv_n;
    float var = stats[K + tid] * inv_n - mean * mean;
    float sc = gamma[tid] * rsqrtf(var + 1e-5f);
    scl[tid] = sc;
    shl[tid] = beta[tid] - mean * sc;
  }
  const int bm = blockIdx.x * 128;
  const int wave = tid >> 6, lane = tid & 63;
  const int wr = wave * 32;
  const int lr = lane & 15;
  const int lk = (lane >> 4) * 8;
  constexpr int NF = TN / 16;

  f32x4 acc[2][NF];
#pragma unroll
  for (int m = 0; m < 2; ++m)
#pragma unroll
    for (int n = 0; n < NF; ++n)
#pragma unroll
      for (int q = 0; q < 4; ++q) acc[m][n][q] = 0.f;
  __syncthreads();

  for (int k0 = 0; k0 < K; k0 += 32) {
#pragma unroll
    for (int it = 0; it < 2; ++it) {
      int s = tid + it * 256;
      int r = s >> 2;
      int c = (s & 3) * 8;
      int grow = bm + r; if (grow >= M) grow = M - 1;
      int4 v = *reinterpret_cast<const int4*>(&A[(size_t)grow * K + k0 + c]);
      ushort* u = reinterpret_cast<ushort*>(&v);
      ushort tmp[8];
#pragma unroll
      for (int j = 0; j < 8; ++j) {
        float f = bf2f(u[j]) * scl[k0 + c + j] + shl[k0 + c + j];
        tmp[j] = f2bf(f >= 0.f ? f : 0.01f * f);
      }
      *reinterpret_cast<int4*>(&As[r][c]) = *reinterpret_cast<int4*>(tmp);
    }
    if (tid < TN * 4) {
      int r = tid >> 2;
      int c = (tid & 3) * 8;
      int4 v = *reinterpret_cast<const int4*>(&BT[(size_t)r * K + k0 + c]);
      *reinterpret_cast<int4*>(&Bs[r][c]) = v;
    }
    __syncthreads();

    bf16x8 af[2], bfr[NF];
#pragma unroll
    for (int m = 0; m < 2; ++m)
      af[m] = *reinterpret_cast<const bf16x8*>(&As[wr + m * 16 + lr][lk]);
#pragma unroll
    for (int n = 0; n < NF; ++n)
      bfr[n] = *reinterpret_cast<const bf16x8*>(&Bs[n * 16 + lr][lk]);
#pragma unroll
    for (int m = 0; m < 2; ++m)
#pragma unroll
      for (int n = 0; n < NF; ++n)
        acc[m][n] = __builtin_amdgcn_mfma_f32_16x16x32_bf16(af[m], bfr[n], acc[m][n], 0, 0, 0);
    __syncthreads();
  }

  const int rbase = (lane >> 4) * 4;
  const int cbase = lane & 15;
#pragma unroll
  for (int m = 0; m < 2; ++m) {
#pragma unroll
    for (int q = 0; q < 4; ++q) {
      int row = bm + wr + m * 16 + rbase + q;
      if (row >= M) continue;
      float sc = rowscale ? rowscale[row] : 1.f;
#pragma unroll
      for (int n = 0; n < NF; ++n) {
        int col = n * 16 + cbase;
        C[(size_t)row * TN + col] = f2bf(acc[m][n][q] * sc);
      }
    }
  }
}

// ---------------- GCN agg + fused BN stats (int4 gathers, x4 unroll) ----------------
template <int F>
__global__ __launch_bounds__(256) void gcn_agg_stats(const ushort* __restrict__ h,
                                                     const int* __restrict__ row_start,
                                                     const int* __restrict__ csr,
                                                     const float* __restrict__ dinv,
                                                     ushort* __restrict__ out,
                                                     float* __restrict__ partials, int n) {
  constexpr int LPN = F / 8;
  constexpr int NPB = 256 / LPN;
  const int tid = threadIdx.x;
  const int sub = tid / LPN;
  const int f8 = (tid % LPN) * 8;
  float ps[8], pq[8];
#pragma unroll
  for (int j = 0; j < 8; ++j) { ps[j] = 0.f; pq[j] = 0.f; }

  for (int node = blockIdx.x * NPB + sub; node < n; node += GSTAT * NPB) {
    float di = dinv[node];
    float a[8];
    {
      int4 v = *reinterpret_cast<const int4*>(&h[(size_t)node * F + f8]);
      const ushort* u = reinterpret_cast<const ushort*>(&v);
#pragma unroll
      for (int j = 0; j < 8; ++j) a[j] = bf2f(u[j]);
    }
    int s0 = row_start[node], s1 = row_start[node + 1];
    int e = s0;
    for (; e + 3 < s1; e += 4) {
      int sA = csr[e], sB = csr[e + 1], sC = csr[e + 2], sD = csr[e + 3];
      int4 vA = *reinterpret_cast<const int4*>(&h[(size_t)sA * F + f8]);
      int4 vB = *reinterpret_cast<const int4*>(&h[(size_t)sB * F + f8]);
      int4 vC = *reinterpret_cast<const int4*>(&h[(size_t)sC * F + f8]);
      int4 vD = *reinterpret_cast<const int4*>(&h[(size_t)sD * F + f8]);
      const ushort* uA = reinterpret_cast<const ushort*>(&vA);
      const ushort* uB = reinterpret_cast<const ushort*>(&vB);
      const ushort* uC = reinterpret_cast<const ushort*>(&vC);
      const ushort* uD = reinterpret_cast<const ushort*>(&vD);
#pragma unroll
      for (int j = 0; j < 8; ++j)
        a[j] += (bf2f(uA[j]) + bf2f(uB[j])) + (bf2f(uC[j]) + bf2f(uD[j]));
    }
    for (; e < s1; ++e) {
      int sA = csr[e];
      int4 vA = *reinterpret_cast<const int4*>(&h[(size_t)sA * F + f8]);
      const ushort* uA = reinterpret_cast<const ushort*>(&vA);
#pragma unroll
      for (int j = 0; j < 8; ++j) a[j] += bf2f(uA[j]);
    }
    ushort u[8];
#pragma unroll
    for (int j = 0; j < 8; ++j) {
      a[j] *= di;
      u[j] = f2bf(a[j]);
      ps[j] += a[j];
      pq[j] += a[j] * a[j];
    }
    *reinterpret_cast<int4*>(&out[(size_t)node * F + f8]) = *reinterpret_cast<int4*>(u);
  }

  __shared__ float red[NPB][2 * F];
#pragma unroll
  for (int j = 0; j < 8; ++j) {
    red[sub][f8 + j] = ps[j];
    red[sub][F + f8 + j] = pq[j];
  }
  __syncthreads();
  for (int c = tid; c < 2 * F; c += 256) {
    float t = 0.f;
#pragma unroll 4
    for (int s = 0; s < NPB; ++s) t += red[s][c];
    partials[(size_t)c * GSTAT + blockIdx.x] = t;
  }
}

// ---------------- GAT softmax: writes NORMALIZED weights (incl. 0.25/den) ----------------
__global__ __launch_bounds__(256) void gat_softmax_norm(const int* __restrict__ row_start,
                                                        const int* __restrict__ csr,
                                                        const float* __restrict__ asc,
                                                        const float* __restrict__ adc,
                                                        float* __restrict__ alpha,
                                                        float* __restrict__ wnorm, int n) {
  int i = blockIdx.x * 256 + threadIdx.x;
  if (i >= 4 * n) return;
  int node = i >> 2, h = i & 3;
  int s0 = row_start[node], s1 = row_start[node + 1];
  float ad = adc[i];
  float eself = lrelu02(asc[i] + ad);
  float m = eself;
  for (int e = s0; e < s1; ++e) {
    float v = lrelu02(asc[csr[e] * 4 + h] + ad);
    alpha[(size_t)e * 4 + h] = v;
    m = fmaxf(m, v);
  }
  float ws = __expf(eself - m);
  float den = ws;
  for (int e = s0; e < s1; ++e) {
    float w = __expf(alpha[(size_t)e * 4 + h] - m);
    alpha[(size_t)e * 4 + h] = w;
    den += w;
  }
  float coef = 0.25f / (den + 1e-16f);
  wnorm[i] = ws * coef;
  for (int e = s0; e < s1; ++e) alpha[(size_t)e * 4 + h] *= coef;
}

// ---------------- GAT agg v3: head-lane int4 gather, 4-edge unroll + BN stats ----------------
// lane = h*16 + l; per edge: one int4 (8 features of head h) + one broadcast float
__global__ __launch_bounds__(256) void gat_agg_v3(const ushort* __restrict__ hg,
                                                  const int* __restrict__ row_start,
                                                  const int* __restrict__ csr,
                                                  const float* __restrict__ alpha,
                                                  const float* __restrict__ wnorm,
                                                  ushort* __restrict__ out,
                                                  float* __restrict__ partials, int n) {
  const int tid = threadIdx.x;
  const int wave = tid >> 6, lane = tid & 63;
  const int h = lane >> 4;
  const int l = lane & 15;
  const int f8 = l * 8;
  float ps[8], pq[8];
#pragma unroll
  for (int j = 0; j < 8; ++j) { ps[j] = 0.f; pq[j] = 0.f; }

  const ushort* base = hg + h * 128 + f8;
  for (int node = blockIdx.x * 4 + wave; node < n; node += GSTAT * 4) {
    float a[8];
    {
      float w = wnorm[node * 4 + h];
      int4 v = *reinterpret_cast<const int4*>(base + (size_t)node * 512);
      const ushort* u = reinterpret_cast<const ushort*>(&v);
#pragma unroll
      for (int j = 0; j < 8; ++j) a[j] = w * bf2f(u[j]);
    }
    int s0 = row_start[node], s1 = row_start[node + 1];
    int e = s0;
    for (; e + 3 < s1; e += 4) {
      int sA = csr[e], sB = csr[e + 1], sC = csr[e + 2], sD = csr[e + 3];
      float wA = alpha[(size_t)e * 4 + h];
      float wB = alpha[(size_t)(e + 1) * 4 + h];
      float wC = alpha[(size_t)(e + 2) * 4 + h];
      float wD = alpha[(size_t)(e + 3) * 4 + h];
      int4 vA = *reinterpret_cast<const int4*>(base + (size_t)sA * 512);
      int4 vB = *reinterpret_cast<const int4*>(base + (size_t)sB * 512);
      int4 vC = *reinterpret_cast<const int4*>(base + (size_t)sC * 512);
      int4 vD = *reinterpret_cast<const int4*>(base + (size_t)sD * 512);
      const ushort* uA = reinterpret_cast<const ushort*>(&vA);
      const ushort* uB = reinterpret_cast<const ushort*>(&vB);
      const ushort* uC = reinterpret_cast<const ushort*>(&vC);
      const ushort* uD = reinterpret_cast<const ushort*>(&vD);
#pragma unroll
      for (int j = 0; j < 8; ++j)
        a[j] += (wA * bf2f(uA[j]) + wB * bf2f(uB[j]))
              + (wC * bf2f(uC[j]) + wD * bf2f(uD[j]));
    }
    for (; e < s1; ++e) {
      int sA = csr[e];
      float wA = alpha[(size_t)e * 4 + h];
      int4 vA = *reinterpret_cast<const int4*>(base + (size_t)sA * 512);
      const ushort* uA = reinterpret_cast<const ushort*>(&vA);
#pragma unroll
      for (int j = 0; j < 8; ++j) a[j] += wA * bf2f(uA[j]);
    }
    // cross-head sum (weights already include 0.25/den)
#pragma unroll
    for (int j = 0; j < 8; ++j) {
      a[j] += __shfl_xor(a[j], 16);
      a[j] += __shfl_xor(a[j], 32);
    }
    if (h == 0) {
      ushort u[8];
#pragma unroll
      for (int j = 0; j < 8; ++j) {
        u[j] = f2bf(a[j]);
        ps[j] += a[j];
        pq[j] += a[j] * a[j];
      }
      *reinterpret_cast<int4*>(&out[(size_t)node * 128 + f8]) = *reinterpret_cast<int4*>(u);
    }
  }

  __shared__ float red[4][256];
  if (h == 0) {
#pragma unroll
    for (int j = 0; j < 8; ++j) {
      red[wave][f8 + j] = ps[j];
      red[wave][128 + f8 + j] = pq[j];
    }
  }
  __syncthreads();
  {
    int c = tid;
    float t = red[0][c] + red[1][c] + red[2][c] + red[3][c];
    partials[(size_t)c * GSTAT + blockIdx.x] = t;
  }
}

// ---------------- stats reduce: one block per column ----------------
__global__ __launch_bounds__(256) void bn_reduce_col(const float* __restrict__ partials,
                                                     float* __restrict__ stats) {
  int c = blockIdx.x;
  float s = 0.f;
  for (int b = threadIdx.x; b < GSTAT; b += 256) s += partials[(size_t)c * GSTAT + b];
#pragma unroll
  for (int off = 32; off > 0; off >>= 1) s += __shfl_down(s, off);
  __shared__ float ws[4];
  if ((threadIdx.x & 63) == 0) ws[threadIdx.x >> 6] = s;
  __syncthreads();
  if (threadIdx.x == 0) stats[c] = ws[0] + ws[1] + ws[2] + ws[3];
}

// ---------------- GAT scores ----------------
__global__ __launch_bounds__(256) void gat_scores_bf(const ushort* __restrict__ hg,
                                                     const float* __restrict__ a_src,
                                                     const float* __restrict__ a_dst,
                                                     float* __restrict__ asc,
                                                     float* __restrict__ adc, int n) {
  int node = blockIdx.x;
  int head = threadIdx.x >> 6;
  int lane = threadIdx.x & 63;
  ushort2 v = *reinterpret_cast<const ushort2*>(&hg[(size_t)node * 512 + head * 128 + lane * 2]);
  float v0 = bf2f(v.x), v1 = bf2f(v.y);
  float s = v0 * a_src[head * 128 + lane * 2] + v1 * a_src[head * 128 + lane * 2 + 1];
  float d = v0 * a_dst[head * 128 + lane * 2] + v1 * a_dst[head * 128 + lane * 2 + 1];
#pragma unroll
  for (int off = 32; off > 0; off >>= 1) {
    s += __shfl_down(s, off);
    d += __shfl_down(d, off);
  }
  if (lane == 0) {
    asc[node * 4 + head] = s;
    adc[node * 4 + head] = d;
  }
}

// ---------------- FC head: fused BN+lrelu + MLP + log_softmax ----------------
__global__ __launch_bounds__(256) void head_kernel_bn(const ushort* __restrict__ h,
                                                      const float* __restrict__ stats,
                                                      const float* __restrict__ g5,
                                                      const float* __restrict__ be5,
                                                      const float* __restrict__ fw1,
                                                      const float* __restrict__ fb1,
                                                      const float* __restrict__ fw2,
                                                      const float* __restrict__ fb2,
                                                      float* __restrict__ out, int n) {
  __shared__ float scl[16], shl[16];
  if (threadIdx.x < 16) {
    const float inv_n = 1.0f / (float)NN;
    int k = threadIdx.x;
    float mean = stats[k] * inv_n;
    float var = stats[16 + k] * inv_n - mean * mean;
    float sc = g5[k] * rsqrtf(var + 1e-5f);
    scl[k] = sc;
    shl[k] = be5[k] - mean * sc;
  }
  __syncthreads();
  int i = blockIdx.x * 256 + threadIdx.x;
  if (i >= n) return;
  int4 ra = *reinterpret_cast<const int4*>(&h[(size_t)i * 16]);
  int4 rb = *reinterpret_cast<const int4*>(&h[(size_t)i * 16 + 8]);
  ushort u[16];
  *reinterpret_cast<int4*>(&u[0]) = ra;
  *reinterpret_cast<int4*>(&u[8]) = rb;
  float xr[16];
#pragma unroll
  for (int k = 0; k < 16; ++k) {
    float v = bf2f(u[k]) * scl[k] + shl[k];
    xr[k] = v >= 0.f ? v : 0.01f * v;
  }
  float z[8];
#pragma unroll
  for (int j = 0; j < 8; ++j) z[j] = fb1[j];
#pragma unroll
  for (int k = 0; k < 16; ++k) {
    float a = xr[k];
#pragma unroll
    for (int j = 0; j < 8; ++j) z[j] += a * fw1[k * 8 + j];
  }
#pragma unroll
  for (int j = 0; j < 8; ++j) z[j] = lrelu01(z[j]);
  float l[3];
#pragma unroll
  for (int j = 0; j < 3; ++j) l[j] = fb2[j];
#pragma unroll
  for (int k = 0; k < 8; ++k) {
    float a = z[k];
#pragma unroll
    for (int j = 0; j < 3; ++j) l[j] += a * fw2[k * 3 + j];
  }
  float mx = fmaxf(l[0], fmaxf(l[1], l[2]));
  float se = __expf(l[0] - mx) + __expf(l[1] - mx) + __expf(l[2] - mx);
  float ls = __logf(se);
#pragma unroll
  for (int j = 0; j < 3; ++j) out[(size_t)i * 3 + j] = l[j] - mx - ls;
}

// ---------------- launch ----------------
extern "C" void kernel_launch(void* const* d_in, const int* in_sizes, int n_in,
                              void* d_out, int out_size, void* d_ws, size_t ws_size,
                              hipStream_t stream) {
  const float* x      = (const float*)d_in[0];
  const int*   ei     = (const int*)d_in[1];
  const int*   srcI   = ei;
  const int*   dstI   = ei + NE;
  const float* w1     = (const float*)d_in[2];
  const float* g1     = (const float*)d_in[4];
  const float* be1    = (const float*)d_in[5];
  const float* gat_w  = (const float*)d_in[6];
  const float* gat_as = (const float*)d_in[7];
  const float* gat_ad = (const float*)d_in[8];
  const float* g2     = (const float*)d_in[10];
  const float* be2    = (const float*)d_in[11];
  const float* w3     = (const float*)d_in[12];
  const float* g3     = (const float*)d_in[14];
  const float* be3    = (const float*)d_in[15];
  const float* w4     = (const float*)d_in[16];
  const float* g4     = (const float*)d_in[18];
  const float* be4    = (const float*)d_in[19];
  const float* w5     = (const float*)d_in[20];
  const float* g5     = (const float*)d_in[22];
  const float* be5    = (const float*)d_in[23];
  const float* fw1    = (const float*)d_in[24];
  const float* fb1    = (const float*)d_in[25];
  const float* fw2    = (const float*)d_in[26];
  const float* fb2    = (const float*)d_in[27];
  float* out = (float*)d_out;

  char* wsp = (char*)d_ws;
  size_t off = 0;
  auto alloc = [&](size_t bytes) -> void* {
    void* p = wsp + off;
    off += (bytes + 255) & ~(size_t)255;
    return p;
  };
  ushort* hw_bf  = (ushort*)alloc((size_t)NN * 512 * 2);
  ushort* r1     = (ushort*)alloc((size_t)NN * 256 * 2);
  ushort* r2     = (ushort*)alloc((size_t)NN * 128 * 2);
  ushort* r3     = (ushort*)alloc((size_t)NN * 64 * 2);
  ushort* r4     = (ushort*)alloc((size_t)NN * 32 * 2);
  ushort* r5     = (ushort*)alloc((size_t)NN * 16 * 2);
  ushort* w1T    = (ushort*)alloc((size_t)256 * 256 * 2);
  ushort* gwT    = (ushort*)alloc((size_t)512 * 256 * 2);
  ushort* w3T    = (ushort*)alloc((size_t)64 * 128 * 2);
  ushort* w4T    = (ushort*)alloc((size_t)32 * 64 * 2);
  ushort* w5T    = (ushort*)alloc((size_t)16 * 32 * 2);
  float*  dinv   = (float*)alloc((size_t)NN * 4);
  int*    counts = (int*)alloc((size_t)NN * 4);
  int*    cursor = (int*)alloc((size_t)NN * 4);
  int*    rstart = (int*)alloc((size_t)(NN + 4) * 4);
  int*    bsum   = (int*)alloc((size_t)256 * 4);
  int*    csr    = (int*)alloc((size_t)NE * 4);
  float*  asc    = (float*)alloc((size_t)NN * 4 * 4);
  float*  adc    = (float*)alloc((size_t)NN * 4 * 4);
  float*  wnorm  = (float*)alloc((size_t)NN * 4 * 4);
  float*  alpha  = (float*)alloc((size_t)NE * 4 * 4);
  float*  stats  = (float*)alloc(2048);
  float*  partials = (float*)alloc((size_t)512 * GSTAT * 4);

  const int egrid = (NE + 255) / 256;
  const int ngrid = (NN + 255) / 256;     // 196
  const int mblocks = (NN + 127) / 128;   // 391

  // CSR build
  hipMemsetAsync(counts, 0, (size_t)NN * 4, stream);
  hipMemsetAsync(cursor, 0, (size_t)NN * 4, stream);
  count_kernel<<<egrid, 256, 0, stream>>>(dstI, counts, NE);
  block_count_sum<<<ngrid, 256, 0, stream>>>(counts, bsum, dinv, NN);
  scan_bsum<<<1, 256, 0, stream>>>(bsum, ngrid);
  row_start_kernel<<<ngrid, 256, 0, stream>>>(counts, bsum, rstart, NN);
  fill_kernel<<<egrid, 256, 0, stream>>>(srcI, dstI, rstart, cursor, csr, NE);

  // weight prep
  wprep<<<810, 256, 0, stream>>>(w1, gat_w, w3, w4, w5, w1T, gwT, w3T, w4T, w5T);

  // ---- Layer 1: GCN 256 -> 256 ----
  gemm_mfma_x<<<dim3(mblocks, 2), 256, 0, stream>>>(x, w1T, hw_bf, NN, 256, 256, dinv);
  gcn_agg_stats<256><<<GSTAT, 256, 0, stream>>>(hw_bf, rstart, csr, dinv, r1, partials, NN);
  bn_reduce_col<<<512, 256, 0, stream>>>(partials, stats);

  // ---- Layer 2: GAT 256 -> 128 (BN1+lrelu fused into A-staging) ----
  gemm_mfma_bn<<<dim3(mblocks, 4), 256, 0, stream>>>(r1, gwT, hw_bf, NN, 256, 512, nullptr,
                                                     stats, g1, be1);
  gat_scores_bf<<<NN, 256, 0, stream>>>(hw_bf, gat_as, gat_ad, asc, adc, NN);
  gat_softmax_norm<<<(4 * NN + 255) / 256, 256, 0, stream>>>(rstart, csr, asc, adc, alpha, wnorm, NN);
  gat_agg_v3<<<GSTAT, 256, 0, stream>>>(hw_bf, rstart, csr, alpha, wnorm, r2, partials, NN);
  bn_reduce_col<<<256, 256, 0, stream>>>(partials, stats);

  // ---- Layer 3: GCN 128 -> 64 (BN2 fused) ----
  gemm_mfma_n_bn<64><<<mblocks, 256, 0, stream>>>(r2, w3T, hw_bf, NN, 128, dinv, stats, g2, be2);
  gcn_agg_stats<64><<<GSTAT, 256, 0, stream>>>(hw_bf, rstart, csr, dinv, r3, partials, NN);
  bn_reduce_col<<<128, 256, 0, stream>>>(partials, stats);

  // ---- Layer 4: GCN 64 -> 32 (BN3 fused) ----
  gemm_mfma_n_bn<32><<<mblocks, 256, 0, stream>>>(r3, w4T, hw_bf, NN, 64, dinv, stats, g3, be3);
  gcn_agg_stats<32><<<GSTAT, 256, 0, stream>>>(hw_bf, rstart, csr, dinv, r4, partials, NN);
  bn_reduce_col<<<64, 256, 0, stream>>>(partials, stats);

  // ---- Layer 5: GCN 32 -> 16 (BN4 fused) ----
  gemm_mfma_n_bn<16><<<mblocks, 256, 0, stream>>>(r4, w5T, hw_bf, NN, 32, dinv, stats, g4, be4);
  gcn_agg_stats<16><<<GSTAT, 256, 0, stream>>>(hw_bf, rstart, csr, dinv, r5, partials, NN);
  bn_reduce_col<<<32, 256, 0, stream>>>(partials, stats);

  // ---- FC head (BN5 fused) + log_softmax ----
  head_kernel_bn<<<ngrid, 256, 0, stream>>>(r5, stats, g5, be5, fw1, fb1, fw2, fb2, out, NN);
}

// Round 10
// 361.047 us; speedup vs baseline: 1.1016x; 1.0728x over previous
//
#include <hip/hip_runtime.h>

#define NN 50000
#define NE 400000
#define GSTAT 2048

typedef short bf16x8 __attribute__((ext_vector_type(8)));
typedef float f32x4 __attribute__((ext_vector_type(4)));

__device__ __forceinline__ float lrelu01(float v) { return v >= 0.f ? v : 0.01f * v; }
__device__ __forceinline__ float lrelu02(float v) { return v >= 0.f ? v : 0.2f * v; }

__device__ __forceinline__ ushort f2bf(float f) {
  union { float f; unsigned u; } v; v.f = f;
  unsigned u = v.u;
  return (ushort)((u + 0x7FFFu + ((u >> 16) & 1u)) >> 16);
}
__device__ __forceinline__ float bf2f(ushort u) {
  union { unsigned u; float f; } v; v.u = ((unsigned)u) << 16;
  return v.f;
}

// ---------------- weight prep: all 5 transposes fused ----------------
__global__ void wprep(const float* __restrict__ w1, const float* __restrict__ gw,
                      const float* __restrict__ w3, const float* __restrict__ w4,
                      const float* __restrict__ w5,
                      ushort* __restrict__ w1T, ushort* __restrict__ gwT,
                      ushort* __restrict__ w3T, ushort* __restrict__ w4T,
                      ushort* __restrict__ w5T) {
  int i = blockIdx.x * 256 + threadIdx.x;
  const float* W; ushort* WT; int K, N, j;
  if (i < 65536)        { W = w1; WT = w1T; K = 256; N = 256; j = i; }
  else if (i < 196608)  { W = gw; WT = gwT; K = 256; N = 512; j = i - 65536; }
  else if (i < 204800)  { W = w3; WT = w3T; K = 128; N = 64;  j = i - 196608; }
  else if (i < 206848)  { W = w4; WT = w4T; K = 64;  N = 32;  j = i - 204800; }
  else if (i < 207360)  { W = w5; WT = w5T; K = 32;  N = 16;  j = i - 206848; }
  else return;
  int k = j / N, c = j % N;
  WT[(size_t)c * K + k] = f2bf(W[(size_t)j]);
}

// ---------------- CSR build ----------------
__global__ void zero2(int* __restrict__ a, int* __restrict__ b, int n) {
  int i = blockIdx.x * 256 + threadIdx.x;
  if (i < n) { a[i] = 0; b[i] = 0; }
}

__global__ void count_kernel(const int* __restrict__ dst, int* __restrict__ counts, int e) {
  int i = blockIdx.x * 256 + threadIdx.x;
  if (i < e) atomicAdd(&counts[dst[i]], 1);
}

__global__ __launch_bounds__(256) void block_count_sum(const int* __restrict__ counts,
                                                       int* __restrict__ bsum,
                                                       float* __restrict__ dinv, int n) {
  int i = blockIdx.x * 256 + threadIdx.x;
  int c = (i < n) ? counts[i] : 0;
  if (i < n) dinv[i] = rsqrtf((float)c + 1.0f);
  int s = c;
#pragma unroll
  for (int off = 32; off > 0; off >>= 1) s += __shfl_down(s, off);
  __shared__ int ws[4];
  if ((threadIdx.x & 63) == 0) ws[threadIdx.x >> 6] = s;
  __syncthreads();
  if (threadIdx.x == 0) bsum[blockIdx.x] = ws[0] + ws[1] + ws[2] + ws[3];
}

__global__ __launch_bounds__(256) void scan_bsum(int* __restrict__ bsum, int nb) {
  __shared__ int sh[256];
  int v = (threadIdx.x < nb) ? bsum[threadIdx.x] : 0;
  sh[threadIdx.x] = v;
  __syncthreads();
  for (int off = 1; off < 256; off <<= 1) {
    int t = (threadIdx.x >= off) ? sh[threadIdx.x - off] : 0;
    __syncthreads();
    sh[threadIdx.x] += t;
    __syncthreads();
  }
  if (threadIdx.x < nb) bsum[threadIdx.x] = sh[threadIdx.x] - v;
}

__global__ __launch_bounds__(256) void row_start_kernel(const int* __restrict__ counts,
                                                        const int* __restrict__ bsum,
                                                        int* __restrict__ row_start, int n) {
  __shared__ int sh[256];
  int i = blockIdx.x * 256 + threadIdx.x;
  int c = (i < n) ? counts[i] : 0;
  sh[threadIdx.x] = c;
  __syncthreads();
  for (int off = 1; off < 256; off <<= 1) {
    int t = (threadIdx.x >= off) ? sh[threadIdx.x - off] : 0;
    __syncthreads();
    sh[threadIdx.x] += t;
    __syncthreads();
  }
  int incl = sh[threadIdx.x];
  int base = bsum[blockIdx.x];
  if (i < n) row_start[i] = base + incl - c;
  if (i == n - 1) row_start[n] = base + incl;
}

__global__ void fill_kernel(const int* __restrict__ src, const int* __restrict__ dst,
                            const int* __restrict__ row_start, int* __restrict__ cursor,
                            int* __restrict__ csr, int e) {
  int i = blockIdx.x * 256 + threadIdx.x;
  if (i >= e) return;
  int d = dst[i];
  int pos = atomicAdd(&cursor[d], 1);
  csr[row_start[d] + pos] = src[i];
}

// ---------------- GEMM 1: A fp32 (x), bf16 out, rowscale ----------------
__global__ __launch_bounds__(256) void gemm_mfma_x(const float* __restrict__ A,
                                                   const ushort* __restrict__ BT,
                                                   ushort* __restrict__ C,
                                                   int M, int K, int N,
                                                   const float* __restrict__ rowscale) {
  __shared__ ushort As[128][40];
  __shared__ ushort Bs[128][40];
  const int tid = threadIdx.x;
  const int bm = blockIdx.x * 128;
  const int bn = blockIdx.y * 128;
  const int wave = tid >> 6, lane = tid & 63;
  const int wr = (wave >> 1) * 64;
  const int wc = (wave & 1) * 64;
  const int lr = lane & 15;
  const int lk = (lane >> 4) * 8;

  f32x4 acc[4][4];
#pragma unroll
  for (int m = 0; m < 4; ++m)
#pragma unroll
    for (int n = 0; n < 4; ++n)
#pragma unroll
      for (int q = 0; q < 4; ++q) acc[m][n][q] = 0.f;

  for (int k0 = 0; k0 < K; k0 += 32) {
#pragma unroll
    for (int it = 0; it < 2; ++it) {
      int s = tid + it * 256;
      int r = s >> 2;
      int c = (s & 3) * 8;
      int grow = bm + r; if (grow >= M) grow = M - 1;
      float4 va = *reinterpret_cast<const float4*>(&A[(size_t)grow * K + k0 + c]);
      float4 vb = *reinterpret_cast<const float4*>(&A[(size_t)grow * K + k0 + c + 4]);
      ushort4 lo = make_ushort4(f2bf(va.x), f2bf(va.y), f2bf(va.z), f2bf(va.w));
      ushort4 hi = make_ushort4(f2bf(vb.x), f2bf(vb.y), f2bf(vb.z), f2bf(vb.w));
      *reinterpret_cast<ushort4*>(&As[r][c]) = lo;
      *reinterpret_cast<ushort4*>(&As[r][c + 4]) = hi;
    }
#pragma unroll
    for (int it = 0; it < 2; ++it) {
      int s = tid + it * 256;
      int r = s >> 2;
      int c = (s & 3) * 8;
      int4 v = *reinterpret_cast<const int4*>(&BT[(size_t)(bn + r) * K + k0 + c]);
      *reinterpret_cast<int4*>(&Bs[r][c]) = v;
    }
    __syncthreads();

    bf16x8 af[4], bfr[4];
#pragma unroll
    for (int m = 0; m < 4; ++m)
      af[m] = *reinterpret_cast<const bf16x8*>(&As[wr + m * 16 + lr][lk]);
#pragma unroll
    for (int n = 0; n < 4; ++n)
      bfr[n] = *reinterpret_cast<const bf16x8*>(&Bs[wc + n * 16 + lr][lk]);
#pragma unroll
    for (int m = 0; m < 4; ++m)
#pragma unroll
      for (int n = 0; n < 4; ++n)
        acc[m][n] = __builtin_amdgcn_mfma_f32_16x16x32_bf16(af[m], bfr[n], acc[m][n], 0, 0, 0);
    __syncthreads();
  }

  const int rbase = (lane >> 4) * 4;
  const int cbase = lane & 15;
#pragma unroll
  for (int m = 0; m < 4; ++m) {
#pragma unroll
    for (int q = 0; q < 4; ++q) {
      int row = bm + wr + m * 16 + rbase + q;
      if (row >= M) continue;
      float sc = rowscale ? rowscale[row] : 1.f;
#pragma unroll
      for (int n = 0; n < 4; ++n) {
        int col = bn + wc + n * 16 + cbase;
        C[(size_t)row * N + col] = f2bf(acc[m][n][q] * sc);
      }
    }
  }
}

// ---------------- GAT GEMM: fused BN+lrelu on A + fused attention scores ----------------
// grid.y = head (N=512, 128 cols per block = one head). Computes asc/adc in epilogue.
__global__ __launch_bounds__(256) void gemm_mfma_bn(const ushort* __restrict__ A,
                                                    const ushort* __restrict__ BT,
                                                    ushort* __restrict__ C,
                                                    int M, int K, int N,
                                                    const float* __restrict__ stats,
                                                    const float* __restrict__ gamma,
                                                    const float* __restrict__ beta,
                                                    const float* __restrict__ a_srcg,
                                                    const float* __restrict__ a_dstg,
                                                    float* __restrict__ asc,
                                                    float* __restrict__ adc) {
  __shared__ ushort As[128][40];
  __shared__ ushort Bs[128][40];
  __shared__ float scl[256], shl[256];
  __shared__ float asrc[128], adst[128];
  __shared__ float sred[128][2], dred[128][2];
  const int tid = threadIdx.x;
  const float inv_n = 1.0f / (float)NN;
  for (int k = tid; k < K; k += 256) {
    float mean = stats[k] * inv_n;
    float var = stats[K + k] * inv_n - mean * mean;
    float sc = gamma[k] * rsqrtf(var + 1e-5f);
    scl[k] = sc;
    shl[k] = beta[k] - mean * sc;
  }
  if (tid < 128) {
    asrc[tid] = a_srcg[blockIdx.y * 128 + tid];
    adst[tid] = a_dstg[blockIdx.y * 128 + tid];
  }
  const int bm = blockIdx.x * 128;
  const int bn = blockIdx.y * 128;
  const int wave = tid >> 6, lane = tid & 63;
  const int wr = (wave >> 1) * 64;
  const int wc = (wave & 1) * 64;
  const int lr = lane & 15;
  const int lk = (lane >> 4) * 8;

  f32x4 acc[4][4];
#pragma unroll
  for (int m = 0; m < 4; ++m)
#pragma unroll
    for (int n = 0; n < 4; ++n)
#pragma unroll
      for (int q = 0; q < 4; ++q) acc[m][n][q] = 0.f;
  __syncthreads();

  for (int k0 = 0; k0 < K; k0 += 32) {
#pragma unroll
    for (int it = 0; it < 2; ++it) {
      int s = tid + it * 256;
      int r = s >> 2;
      int c = (s & 3) * 8;
      int grow = bm + r; if (grow >= M) grow = M - 1;
      int4 v = *reinterpret_cast<const int4*>(&A[(size_t)grow * K + k0 + c]);
      ushort* u = reinterpret_cast<ushort*>(&v);
      ushort tmp[8];
#pragma unroll
      for (int j = 0; j < 8; ++j) {
        float f = bf2f(u[j]) * scl[k0 + c + j] + shl[k0 + c + j];
        tmp[j] = f2bf(f >= 0.f ? f : 0.01f * f);
      }
      *reinterpret_cast<int4*>(&As[r][c]) = *reinterpret_cast<int4*>(tmp);
    }
#pragma unroll
    for (int it = 0; it < 2; ++it) {
      int s = tid + it * 256;
      int r = s >> 2;
      int c = (s & 3) * 8;
      int4 v = *reinterpret_cast<const int4*>(&BT[(size_t)(bn + r) * K + k0 + c]);
      *reinterpret_cast<int4*>(&Bs[r][c]) = v;
    }
    __syncthreads();

    bf16x8 af[4], bfr[4];
#pragma unroll
    for (int m = 0; m < 4; ++m)
      af[m] = *reinterpret_cast<const bf16x8*>(&As[wr + m * 16 + lr][lk]);
#pragma unroll
    for (int n = 0; n < 4; ++n)
      bfr[n] = *reinterpret_cast<const bf16x8*>(&Bs[wc + n * 16 + lr][lk]);
#pragma unroll
    for (int m = 0; m < 4; ++m)
#pragma unroll
      for (int n = 0; n < 4; ++n)
        acc[m][n] = __builtin_amdgcn_mfma_f32_16x16x32_bf16(af[m], bfr[n], acc[m][n], 0, 0, 0);
    __syncthreads();
  }

  const int rbase = (lane >> 4) * 4;
  const int cbase = lane & 15;
  // store C (bf16-rounded) and compute per-row score partials from the rounded values
#pragma unroll
  for (int m = 0; m < 4; ++m) {
#pragma unroll
    for (int q = 0; q < 4; ++q) {
      int rloc = wr + m * 16 + rbase + q;
      int row = bm + rloc;
      float s = 0.f, d = 0.f;
#pragma unroll
      for (int n = 0; n < 4; ++n) {
        int colin = wc + n * 16 + cbase;           // 0..127 within this head
        ushort ub = f2bf(acc[m][n][q]);
        float vv = bf2f(ub);
        if (row < M) C[(size_t)row * N + bn + colin] = ub;
        s += vv * asrc[colin];
        d += vv * adst[colin];
      }
      // reduce over the 16 lanes of this lane-group
#pragma unroll
      for (int w = 1; w < 16; w <<= 1) {
        s += __shfl_xor(s, w);
        d += __shfl_xor(d, w);
      }
      if ((lane & 15) == 0) {
        sred[rloc][wave & 1] = s;
        dred[rloc][wave & 1] = d;
      }
    }
  }
  __syncthreads();
  if (tid < 128) {
    int grow = bm + tid;
    if (grow < M) {
      asc[(size_t)grow * 4 + blockIdx.y] = sred[tid][0] + sred[tid][1];
      adc[(size_t)grow * 4 + blockIdx.y] = dred[tid][0] + dred[tid][1];
    }
  }
}

// ---------------- small-N GEMM with fused BN+lrelu on A ----------------
template <int TN>
__global__ __launch_bounds__(256) void gemm_mfma_n_bn(const ushort* __restrict__ A,
                                                      const ushort* __restrict__ BT,
                                                      ushort* __restrict__ C,
                                                      int M, int K,
                                                      const float* __restrict__ rowscale,
                                                      const float* __restrict__ stats,
                                                      const float* __restrict__ gamma,
                                                      const float* __restrict__ beta) {
  __shared__ ushort As[128][40];
  __shared__ ushort Bs[TN][40];
  __shared__ float scl[128], shl[128];
  const int tid = threadIdx.x;
  const float inv_n = 1.0f / (float)NN;
  if (tid < K) {
    float mean = stats[tid] * inv_n;
    float var = stats[K + tid] * inv_n - mean * mean;
    float sc = gamma[tid] * rsqrtf(var + 1e-5f);
    scl[tid] = sc;
    shl[tid] = beta[tid] - mean * sc;
  }
  const int bm = blockIdx.x * 128;
  const int wave = tid >> 6, lane = tid & 63;
  const int wr = wave * 32;
  const int lr = lane & 15;
  const int lk = (lane >> 4) * 8;
  constexpr int NF = TN / 16;

  f32x4 acc[2][NF];
#pragma unroll
  for (int m = 0; m < 2; ++m)
#pragma unroll
    for (int n = 0; n < NF; ++n)
#pragma unroll
      for (int q = 0; q < 4; ++q) acc[m][n][q] = 0.f;
  __syncthreads();

  for (int k0 = 0; k0 < K; k0 += 32) {
#pragma unroll
    for (int it = 0; it < 2; ++it) {
      int s = tid + it * 256;
      int r = s >> 2;
      int c = (s & 3) * 8;
      int grow = bm + r; if (grow >= M) grow = M - 1;
      int4 v = *reinterpret_cast<const int4*>(&A[(size_t)grow * K + k0 + c]);
      ushort* u = reinterpret_cast<ushort*>(&v);
      ushort tmp[8];
#pragma unroll
      for (int j = 0; j < 8; ++j) {
        float f = bf2f(u[j]) * scl[k0 + c + j] + shl[k0 + c + j];
        tmp[j] = f2bf(f >= 0.f ? f : 0.01f * f);
      }
      *reinterpret_cast<int4*>(&As[r][c]) = *reinterpret_cast<int4*>(tmp);
    }
    if (tid < TN * 4) {
      int r = tid >> 2;
      int c = (tid & 3) * 8;
      int4 v = *reinterpret_cast<const int4*>(&BT[(size_t)r * K + k0 + c]);
      *reinterpret_cast<int4*>(&Bs[r][c]) = v;
    }
    __syncthreads();

    bf16x8 af[2], bfr[NF];
#pragma unroll
    for (int m = 0; m < 2; ++m)
      af[m] = *reinterpret_cast<const bf16x8*>(&As[wr + m * 16 + lr][lk]);
#pragma unroll
    for (int n = 0; n < NF; ++n)
      bfr[n] = *reinterpret_cast<const bf16x8*>(&Bs[n * 16 + lr][lk]);
#pragma unroll
    for (int m = 0; m < 2; ++m)
#pragma unroll
      for (int n = 0; n < NF; ++n)
        acc[m][n] = __builtin_amdgcn_mfma_f32_16x16x32_bf16(af[m], bfr[n], acc[m][n], 0, 0, 0);
    __syncthreads();
  }

  const int rbase = (lane >> 4) * 4;
  const int cbase = lane & 15;
#pragma unroll
  for (int m = 0; m < 2; ++m) {
#pragma unroll
    for (int q = 0; q < 4; ++q) {
      int row = bm + wr + m * 16 + rbase + q;
      if (row >= M) continue;
      float sc = rowscale ? rowscale[row] : 1.f;
#pragma unroll
      for (int n = 0; n < NF; ++n) {
        int col = n * 16 + cbase;
        C[(size_t)row * TN + col] = f2bf(acc[m][n][q] * sc);
      }
    }
  }
}

// ---------------- GCN agg + fused BN stats (int4 gathers, x4 unroll) ----------------
template <int F>
__global__ __launch_bounds__(256) void gcn_agg_stats(const ushort* __restrict__ h,
                                                     const int* __restrict__ row_start,
                                                     const int* __restrict__ csr,
                                                     const float* __restrict__ dinv,
                                                     ushort* __restrict__ out,
                                                     float* __restrict__ partials, int n) {
  constexpr int LPN = F / 8;
  constexpr int NPB = 256 / LPN;
  const int tid = threadIdx.x;
  const int sub = tid / LPN;
  const int f8 = (tid % LPN) * 8;
  float ps[8], pq[8];
#pragma unroll
  for (int j = 0; j < 8; ++j) { ps[j] = 0.f; pq[j] = 0.f; }

  for (int node = blockIdx.x * NPB + sub; node < n; node += GSTAT * NPB) {
    float di = dinv[node];
    float a[8];
    {
      int4 v = *reinterpret_cast<const int4*>(&h[(size_t)node * F + f8]);
      const ushort* u = reinterpret_cast<const ushort*>(&v);
#pragma unroll
      for (int j = 0; j < 8; ++j) a[j] = bf2f(u[j]);
    }
    int s0 = row_start[node], s1 = row_start[node + 1];
    int e = s0;
    for (; e + 3 < s1; e += 4) {
      int sA = csr[e], sB = csr[e + 1], sC = csr[e + 2], sD = csr[e + 3];
      int4 vA = *reinterpret_cast<const int4*>(&h[(size_t)sA * F + f8]);
      int4 vB = *reinterpret_cast<const int4*>(&h[(size_t)sB * F + f8]);
      int4 vC = *reinterpret_cast<const int4*>(&h[(size_t)sC * F + f8]);
      int4 vD = *reinterpret_cast<const int4*>(&h[(size_t)sD * F + f8]);
      const ushort* uA = reinterpret_cast<const ushort*>(&vA);
      const ushort* uB = reinterpret_cast<const ushort*>(&vB);
      const ushort* uC = reinterpret_cast<const ushort*>(&vC);
      const ushort* uD = reinterpret_cast<const ushort*>(&vD);
#pragma unroll
      for (int j = 0; j < 8; ++j)
        a[j] += (bf2f(uA[j]) + bf2f(uB[j])) + (bf2f(uC[j]) + bf2f(uD[j]));
    }
    for (; e < s1; ++e) {
      int sA = csr[e];
      int4 vA = *reinterpret_cast<const int4*>(&h[(size_t)sA * F + f8]);
      const ushort* uA = reinterpret_cast<const ushort*>(&vA);
#pragma unroll
      for (int j = 0; j < 8; ++j) a[j] += bf2f(uA[j]);
    }
    ushort u[8];
#pragma unroll
    for (int j = 0; j < 8; ++j) {
      a[j] *= di;
      u[j] = f2bf(a[j]);
      ps[j] += a[j];
      pq[j] += a[j] * a[j];
    }
    *reinterpret_cast<int4*>(&out[(size_t)node * F + f8]) = *reinterpret_cast<int4*>(u);
  }

  __shared__ float red[NPB][2 * F];
#pragma unroll
  for (int j = 0; j < 8; ++j) {
    red[sub][f8 + j] = ps[j];
    red[sub][F + f8 + j] = pq[j];
  }
  __syncthreads();
  for (int c = tid; c < 2 * F; c += 256) {
    float t = 0.f;
#pragma unroll 4
    for (int s = 0; s < NPB; ++s) t += red[s][c];
    partials[(size_t)c * GSTAT + blockIdx.x] = t;
  }
}

// ---------------- GAT softmax: unnormalized exp weights + per-(node,head) coef ----------------
__global__ __launch_bounds__(256) void gat_softmax_norm(const int* __restrict__ row_start,
                                                        const int* __restrict__ csr,
                                                        const float* __restrict__ asc,
                                                        const float* __restrict__ adc,
                                                        float* __restrict__ alpha,
                                                        float* __restrict__ wnorm,
                                                        float* __restrict__ coefs, int n) {
  int i = blockIdx.x * 256 + threadIdx.x;
  if (i >= 4 * n) return;
  int node = i >> 2, h = i & 3;
  int s0 = row_start[node], s1 = row_start[node + 1];
  float ad = adc[i];
  float eself = lrelu02(asc[i] + ad);
  float m = eself;
  for (int e = s0; e < s1; ++e) {
    float v = lrelu02(asc[csr[e] * 4 + h] + ad);
    alpha[(size_t)e * 4 + h] = v;
    m = fmaxf(m, v);
  }
  float ws = __expf(eself - m);
  float den = ws;
  for (int e = s0; e < s1; ++e) {
    float w = __expf(alpha[(size_t)e * 4 + h] - m);
    alpha[(size_t)e * 4 + h] = w;
    den += w;
  }
  wnorm[i] = ws;
  coefs[i] = 0.25f / (den + 1e-16f);
}

// ---------------- GAT agg v3: head-lane int4 gather, 4-edge unroll + BN stats ----------------
__global__ __launch_bounds__(256) void gat_agg_v3(const ushort* __restrict__ hg,
                                                  const int* __restrict__ row_start,
                                                  const int* __restrict__ csr,
                                                  const float* __restrict__ alpha,
                                                  const float* __restrict__ wnorm,
                                                  const float* __restrict__ coefs,
                                                  ushort* __restrict__ out,
                                                  float* __restrict__ partials, int n) {
  const int tid = threadIdx.x;
  const int wave = tid >> 6, lane = tid & 63;
  const int h = lane >> 4;
  const int l = lane & 15;
  const int f8 = l * 8;
  float ps[8], pq[8];
#pragma unroll
  for (int j = 0; j < 8; ++j) { ps[j] = 0.f; pq[j] = 0.f; }

  const ushort* base = hg + h * 128 + f8;
  for (int node = blockIdx.x * 4 + wave; node < n; node += GSTAT * 4) {
    float a[8];
    {
      float w = wnorm[node * 4 + h];
      int4 v = *reinterpret_cast<const int4*>(base + (size_t)node * 512);
      const ushort* u = reinterpret_cast<const ushort*>(&v);
#pragma unroll
      for (int j = 0; j < 8; ++j) a[j] = w * bf2f(u[j]);
    }
    int s0 = row_start[node], s1 = row_start[node + 1];
    int e = s0;
    for (; e + 3 < s1; e += 4) {
      int sA = csr[e], sB = csr[e + 1], sC = csr[e + 2], sD = csr[e + 3];
      float wA = alpha[(size_t)e * 4 + h];
      float wB = alpha[(size_t)(e + 1) * 4 + h];
      float wC = alpha[(size_t)(e + 2) * 4 + h];
      float wD = alpha[(size_t)(e + 3) * 4 + h];
      int4 vA = *reinterpret_cast<const int4*>(base + (size_t)sA * 512);
      int4 vB = *reinterpret_cast<const int4*>(base + (size_t)sB * 512);
      int4 vC = *reinterpret_cast<const int4*>(base + (size_t)sC * 512);
      int4 vD = *reinterpret_cast<const int4*>(base + (size_t)sD * 512);
      const ushort* uA = reinterpret_cast<const ushort*>(&vA);
      const ushort* uB = reinterpret_cast<const ushort*>(&vB);
      const ushort* uC = reinterpret_cast<const ushort*>(&vC);
      const ushort* uD = reinterpret_cast<const ushort*>(&vD);
#pragma unroll
      for (int j = 0; j < 8; ++j)
        a[j] += (wA * bf2f(uA[j]) + wB * bf2f(uB[j]))
              + (wC * bf2f(uC[j]) + wD * bf2f(uD[j]));
    }
    for (; e < s1; ++e) {
      int sA = csr[e];
      float wA = alpha[(size_t)e * 4 + h];
      int4 vA = *reinterpret_cast<const int4*>(base + (size_t)sA * 512);
      const ushort* uA = reinterpret_cast<const ushort*>(&vA);
#pragma unroll
      for (int j = 0; j < 8; ++j) a[j] += wA * bf2f(uA[j]);
    }
    // per-head normalization (0.25/den), then cross-head sum
    float cf = coefs[node * 4 + h];
#pragma unroll
    for (int j = 0; j < 8; ++j) {
      a[j] *= cf;
      a[j] += __shfl_xor(a[j], 16);
      a[j] += __shfl_xor(a[j], 32);
    }
    if (h == 0) {
      ushort u[8];
#pragma unroll
      for (int j = 0; j < 8; ++j) {
        u[j] = f2bf(a[j]);
        ps[j] += a[j];
        pq[j] += a[j] * a[j];
      }
      *reinterpret_cast<int4*>(&out[(size_t)node * 128 + f8]) = *reinterpret_cast<int4*>(u);
    }
  }

  __shared__ float red[4][256];
  if (h == 0) {
#pragma unroll
    for (int j = 0; j < 8; ++j) {
      red[wave][f8 + j] = ps[j];
      red[wave][128 + f8 + j] = pq[j];
    }
  }
  __syncthreads();
  {
    int c = tid;
    float t = red[0][c] + red[1][c] + red[2][c] + red[3][c];
    partials[(size_t)c * GSTAT + blockIdx.x] = t;
  }
}

// ---------------- stats reduce: one block per column ----------------
__global__ __launch_bounds__(256) void bn_reduce_col(const float* __restrict__ partials,
                                                     float* __restrict__ stats) {
  int c = blockIdx.x;
  float s = 0.f;
  for (int b = threadIdx.x; b < GSTAT; b += 256) s += partials[(size_t)c * GSTAT + b];
#pragma unroll
  for (int off = 32; off > 0; off >>= 1) s += __shfl_down(s, off);
  __shared__ float ws[4];
  if ((threadIdx.x & 63) == 0) ws[threadIdx.x >> 6] = s;
  __syncthreads();
  if (threadIdx.x == 0) stats[c] = ws[0] + ws[1] + ws[2] + ws[3];
}

// ---------------- FC head: fused BN+lrelu + MLP + log_softmax ----------------
__global__ __launch_bounds__(256) void head_kernel_bn(const ushort* __restrict__ h,
                                                      const float* __restrict__ stats,
                                                      const float* __restrict__ g5,
                                                      const float* __restrict__ be5,
                                                      const float* __restrict__ fw1,
                                                      const float* __restrict__ fb1,
                                                      const float* __restrict__ fw2,
                                                      const float* __restrict__ fb2,
                                                      float* __restrict__ out, int n) {
  __shared__ float scl[16], shl[16];
  if (threadIdx.x < 16) {
    const float inv_n = 1.0f / (float)NN;
    int k = threadIdx.x;
    float mean = stats[k] * inv_n;
    float var = stats[16 + k] * inv_n - mean * mean;
    float sc = g5[k] * rsqrtf(var + 1e-5f);
    scl[k] = sc;
    shl[k] = be5[k] - mean * sc;
  }
  __syncthreads();
  int i = blockIdx.x * 256 + threadIdx.x;
  if (i >= n) return;
  int4 ra = *reinterpret_cast<const int4*>(&h[(size_t)i * 16]);
  int4 rb = *reinterpret_cast<const int4*>(&h[(size_t)i * 16 + 8]);
  ushort u[16];
  *reinterpret_cast<int4*>(&u[0]) = ra;
  *reinterpret_cast<int4*>(&u[8]) = rb;
  float xr[16];
#pragma unroll
  for (int k = 0; k < 16; ++k) {
    float v = bf2f(u[k]) * scl[k] + shl[k];
    xr[k] = v >= 0.f ? v : 0.01f * v;
  }
  float z[8];
#pragma unroll
  for (int j = 0; j < 8; ++j) z[j] = fb1[j];
#pragma unroll
  for (int k = 0; k < 16; ++k) {
    float a = xr[k];
#pragma unroll
    for (int j = 0; j < 8; ++j) z[j] += a * fw1[k * 8 + j];
  }
#pragma unroll
  for (int j = 0; j < 8; ++j) z[j] = lrelu01(z[j]);
  float l[3];
#pragma unroll
  for (int j = 0; j < 3; ++j) l[j] = fb2[j];
#pragma unroll
  for (int k = 0; k < 8; ++k) {
    float a = z[k];
#pragma unroll
    for (int j = 0; j < 3; ++j) l[j] += a * fw2[k * 3 + j];
  }
  float mx = fmaxf(l[0], fmaxf(l[1], l[2]));
  float se = __expf(l[0] - mx) + __expf(l[1] - mx) + __expf(l[2] - mx);
  float ls = __logf(se);
#pragma unroll
  for (int j = 0; j < 3; ++j) out[(size_t)i * 3 + j] = l[j] - mx - ls;
}

// ---------------- launch ----------------
extern "C" void kernel_launch(void* const* d_in, const int* in_sizes, int n_in,
                              void* d_out, int out_size, void* d_ws, size_t ws_size,
                              hipStream_t stream) {
  const float* x      = (const float*)d_in[0];
  const int*   ei     = (const int*)d_in[1];
  const int*   srcI   = ei;
  const int*   dstI   = ei + NE;
  const float* w1     = (const float*)d_in[2];
  const float* g1     = (const float*)d_in[4];
  const float* be1    = (const float*)d_in[5];
  const float* gat_w  = (const float*)d_in[6];
  const float* gat_as = (const float*)d_in[7];
  const float* gat_ad = (const float*)d_in[8];
  const float* g2     = (const float*)d_in[10];
  const float* be2    = (const float*)d_in[11];
  const float* w3     = (const float*)d_in[12];
  const float* g3     = (const float*)d_in[14];
  const float* be3    = (const float*)d_in[15];
  const float* w4     = (const float*)d_in[16];
  const float* g4     = (const float*)d_in[18];
  const float* be4    = (const float*)d_in[19];
  const float* w5     = (const float*)d_in[20];
  const float* g5     = (const float*)d_in[22];
  const float* be5    = (const float*)d_in[23];
  const float* fw1    = (const float*)d_in[24];
  const float* fb1    = (const float*)d_in[25];
  const float* fw2    = (const float*)d_in[26];
  const float* fb2    = (const float*)d_in[27];
  float* out = (float*)d_out;

  char* wsp = (char*)d_ws;
  size_t off = 0;
  auto alloc = [&](size_t bytes) -> void* {
    void* p = wsp + off;
    off += (bytes + 255) & ~(size_t)255;
    return p;
  };
  ushort* hw_bf  = (ushort*)alloc((size_t)NN * 512 * 2);
  ushort* r1     = (ushort*)alloc((size_t)NN * 256 * 2);
  ushort* r2     = (ushort*)alloc((size_t)NN * 128 * 2);
  ushort* r3     = (ushort*)alloc((size_t)NN * 64 * 2);
  ushort* r4     = (ushort*)alloc((size_t)NN * 32 * 2);
  ushort* r5     = (ushort*)alloc((size_t)NN * 16 * 2);
  ushort* w1T    = (ushort*)alloc((size_t)256 * 256 * 2);
  ushort* gwT    = (ushort*)alloc((size_t)512 * 256 * 2);
  ushort* w3T    = (ushort*)alloc((size_t)64 * 128 * 2);
  ushort* w4T    = (ushort*)alloc((size_t)32 * 64 * 2);
  ushort* w5T    = (ushort*)alloc((size_t)16 * 32 * 2);
  float*  dinv   = (float*)alloc((size_t)NN * 4);
  int*    counts = (int*)alloc((size_t)NN * 4);
  int*    cursor = (int*)alloc((size_t)NN * 4);
  int*    rstart = (int*)alloc((size_t)(NN + 4) * 4);
  int*    bsum   = (int*)alloc((size_t)256 * 4);
  int*    csr    = (int*)alloc((size_t)NE * 4);
  float*  asc    = (float*)alloc((size_t)NN * 4 * 4);
  float*  adc    = (float*)alloc((size_t)NN * 4 * 4);
  float*  wnorm  = (float*)alloc((size_t)NN * 4 * 4);
  float*  coefs  = (float*)alloc((size_t)NN * 4 * 4);
  float*  alpha  = (float*)alloc((size_t)NE * 4 * 4);
  float*  stats  = (float*)alloc(2048);
  float*  partials = (float*)alloc((size_t)512 * GSTAT * 4);

  const int egrid = (NE + 255) / 256;
  const int ngrid = (NN + 255) / 256;     // 196
  const int mblocks = (NN + 127) / 128;   // 391

  // CSR build
  zero2<<<ngrid, 256, 0, stream>>>(counts, cursor, NN);
  count_kernel<<<egrid, 256, 0, stream>>>(dstI, counts, NE);
  block_count_sum<<<ngrid, 256, 0, stream>>>(counts, bsum, dinv, NN);
  scan_bsum<<<1, 256, 0, stream>>>(bsum, ngrid);
  row_start_kernel<<<ngrid, 256, 0, stream>>>(counts, bsum, rstart, NN);
  fill_kernel<<<egrid, 256, 0, stream>>>(srcI, dstI, rstart, cursor, csr, NE);

  // weight prep
  wprep<<<810, 256, 0, stream>>>(w1, gat_w, w3, w4, w5, w1T, gwT, w3T, w4T, w5T);

  // ---- Layer 1: GCN 256 -> 256 ----
  gemm_mfma_x<<<dim3(mblocks, 2), 256, 0, stream>>>(x, w1T, hw_bf, NN, 256, 256, dinv);
  gcn_agg_stats<256><<<GSTAT, 256, 0, stream>>>(hw_bf, rstart, csr, dinv, r1, partials, NN);
  bn_reduce_col<<<512, 256, 0, stream>>>(partials, stats);

  // ---- Layer 2: GAT 256 -> 128 (BN1+lrelu fused into A-staging; scores in epilogue) ----
  gemm_mfma_bn<<<dim3(mblocks, 4), 256, 0, stream>>>(r1, gwT, hw_bf, NN, 256, 512,
                                                     stats, g1, be1, gat_as, gat_ad, asc, adc);
  gat_softmax_norm<<<(4 * NN + 255) / 256, 256, 0, stream>>>(rstart, csr, asc, adc, alpha,
                                                             wnorm, coefs, NN);
  gat_agg_v3<<<GSTAT, 256, 0, stream>>>(hw_bf, rstart, csr, alpha, wnorm, coefs, r2, partials, NN);
  bn_reduce_col<<<256, 256, 0, stream>>>(partials, stats);

  // ---- Layer 3: GCN 128 -> 64 (BN2 fused) ----
  gemm_mfma_n_bn<64><<<mblocks, 256, 0, stream>>>(r2, w3T, hw_bf, NN, 128, dinv, stats, g2, be2);
  gcn_agg_stats<64><<<GSTAT, 256, 0, stream>>>(hw_bf, rstart, csr, dinv, r3, partials, NN);
  bn_reduce_col<<<128, 256, 0, stream>>>(partials, stats);

  // ---- Layer 4: GCN 64 -> 32 (BN3 fused) ----
  gemm_mfma_n_bn<32><<<mblocks, 256, 0, stream>>>(r3, w4T, hw_bf, NN, 64, dinv, stats, g3, be3);
  gcn_agg_stats<32><<<GSTAT, 256, 0, stream>>>(hw_bf, rstart, csr, dinv, r4, partials, NN);
  bn_reduce_col<<<64, 256, 0, stream>>>(partials, stats);

  // ---- Layer 5: GCN 32 -> 16 (BN4 fused) ----
  gemm_mfma_n_bn<16><<<mblocks, 256, 0, stream>>>(r4, w5T, hw_bf, NN, 32, dinv, stats, g4, be4);
  gcn_agg_stats<16><<<GSTAT, 256, 0, stream>>>(hw_bf, rstart, csr, dinv, r5, partials, NN);
  bn_reduce_col<<<32, 256, 0, stream>>>(partials, stats);

  // ---- FC head (BN5 fused) + log_softmax ----
  head_kernel_bn<<<ngrid, 256, 0, stream>>>(r5, stats, g5, be5, fw1, fb1, fw2, fb2, out, NN);
}